// Round 1
// baseline (2172.983 us; speedup 1.0000x reference)
//
#include <hip/hip_runtime.h>
#include <math.h>

// ---------------- CSR build ----------------

__global__ __launch_bounds__(256) void count_kernel(const int* __restrict__ ei,
                                                    int* __restrict__ cnt, int N, int E) {
    int idx = blockIdx.x * 256 + threadIdx.x;
    if (idx >= 5 * E) return;
    int r = idx / E;
    int e = idx - r * E;
    int dst = ei[(size_t)r * 2 * E + E + e];
    atomicAdd(&cnt[r * N + dst], 1);
}

__global__ __launch_bounds__(1024) void scan_kernel(const int* __restrict__ cnt,
                                                    int* __restrict__ off, int N) {
    int r = blockIdx.x, t = threadIdx.x;
    __shared__ int sd[1024];
    __shared__ int run;
    if (t == 0) run = 0;
    __syncthreads();
    for (int base = 0; base < N; base += 1024) {
        int v = (base + t < N) ? cnt[r * N + base + t] : 0;
        sd[t] = v;
        __syncthreads();
        for (int s = 1; s < 1024; s <<= 1) {
            int add = (t >= s) ? sd[t - s] : 0;
            __syncthreads();
            sd[t] += add;
            __syncthreads();
        }
        if (base + t < N) off[(size_t)r * (N + 1) + base + t] = run + sd[t] - v;
        __syncthreads();
        if (t == 1023) run += sd[1023];
        __syncthreads();
    }
    if (t == 0) off[(size_t)r * (N + 1) + N] = run;
}

__global__ __launch_bounds__(256) void scatter_kernel(const int* __restrict__ ei,
                                                      const int* __restrict__ off,
                                                      int* __restrict__ cur,
                                                      int* __restrict__ srcs, int N, int E) {
    int idx = blockIdx.x * 256 + threadIdx.x;
    if (idx >= 5 * E) return;
    int r = idx / E;
    int e = idx - r * E;
    int src = ei[(size_t)r * 2 * E + e];
    int dst = ei[(size_t)r * 2 * E + E + e];
    int pos = atomicAdd(&cur[r * N + dst], 1);
    srcs[(size_t)r * E + off[(size_t)r * (N + 1) + dst] + pos] = src;
}

// ---------------- PEARL PE + time PE + concat -> h0 [N,112] ----------------

__global__ __launch_bounds__(256) void pearl_h0_kernel(
    const float* __restrict__ x, const int* __restrict__ date,
    const int* __restrict__ off, const int* __restrict__ srcs,
    const float* __restrict__ pW, const float* __restrict__ pb,
    float* __restrict__ h0, int N, int E) {
    int lane = threadIdx.x & 63;
    int wid = blockIdx.x * 4 + (threadIdx.x >> 6);
    if (wid >= N) return;
    int n = __builtin_amdgcn_readfirstlane(wid);

    float acc = 0.f;
    int deg = 0;
    for (int r = 0; r < 5; r++) {
        int kb = off[(size_t)r * (N + 1) + n];
        int ke = off[(size_t)r * (N + 1) + n + 1];
        deg += ke - kb;
        const int* sp = srcs + (size_t)r * E;
        for (int k = kb; k < ke; k++) {
            acc += x[(size_t)sp[k] * 64 + lane];
        }
    }
    float an = acc / fmaxf((float)deg, 1.0f);

    // pe[j] = tanh(b[j] + sum_c agg[c]*W[c,j]) via shuffle broadcast of agg
    float s = (lane < 32) ? pb[lane] : 0.f;
#pragma unroll 8
    for (int c = 0; c < 64; c++) {
        float av = __shfl(an, c, 64);
        if (lane < 32) s = fmaf(av, pW[c * 32 + lane], s);
    }

    // writes: [x(64) | pe(32) | tpe(16)]
    h0[(size_t)n * 112 + lane] = x[(size_t)n * 64 + lane];
    if (lane < 32) h0[(size_t)n * 112 + 64 + lane] = tanhf(s);
    if (lane < 16) {
        float t = (float)date[n] / 10000.0f;
        int i = lane & 7;
        // div = exp(-(2i)*ln(10000)/16)
        float dv = expf((float)(2 * i) * (-0.57564627324851148f));
        float arg = t * dv;
        h0[(size_t)n * 112 + 96 + lane] = (lane < 8) ? sinf(arg) : cosf(arg);
    }
}

// ---------------- fp32 tiled GEMM: C = A[M,K] @ B[K,Nout] (+bias,relu) ----------------
// blockIdx.z selects (B0,C0)/(B1,C1) so xl and xr share one launch (A reused).

__global__ __launch_bounds__(256) void gemm_dual(
    const float* __restrict__ A,
    const float* __restrict__ B0, float* __restrict__ C0,
    const float* __restrict__ B1, float* __restrict__ C1,
    int M, int K, int Nout,
    const float* __restrict__ bias, int do_relu) {
    const float* B = (blockIdx.z == 0) ? B0 : B1;
    float* C = (blockIdx.z == 0) ? C0 : C1;
    __shared__ float As[16][68];  // +4 pad: conflict-free writes
    __shared__ float Bs[16][64];
    int tid = threadIdx.x;
    int row0 = blockIdx.x * 64, col0 = blockIdx.y * 64;
    int ty4 = (tid >> 4) << 2, tx4 = (tid & 15) << 2;
    float acc[4][4] = {};

    for (int kt = 0; kt < K; kt += 16) {
#pragma unroll
        for (int i = 0; i < 4; i++) {
            int lin = tid + i * 256;
            int m = lin >> 4, k = lin & 15;
            int row = row0 + m;
            As[k][m] = (row < M) ? A[(size_t)row * K + kt + k] : 0.f;
        }
#pragma unroll
        for (int i = 0; i < 4; i++) {
            int lin = tid + i * 256;
            int k = lin >> 6, c = lin & 63;
            Bs[k][c] = B[(size_t)(kt + k) * Nout + col0 + c];
        }
        __syncthreads();
#pragma unroll
        for (int kk = 0; kk < 16; kk++) {
            float4 a = *(const float4*)&As[kk][ty4];
            float4 b = *(const float4*)&Bs[kk][tx4];
            float av[4] = {a.x, a.y, a.z, a.w};
            float bv[4] = {b.x, b.y, b.z, b.w};
#pragma unroll
            for (int i = 0; i < 4; i++)
#pragma unroll
                for (int j = 0; j < 4; j++)
                    acc[i][j] = fmaf(av[i], bv[j], acc[i][j]);
        }
        __syncthreads();
    }

#pragma unroll
    for (int i = 0; i < 4; i++) {
        int row = row0 + ty4 + i;
        if (row >= M) continue;
#pragma unroll
        for (int j = 0; j < 4; j++) {
            int col = col0 + tx4 + j;
            float v = acc[i][j];
            if (bias) v += bias[col];
            if (do_relu) v = fmaxf(v, 0.f);
            C[(size_t)row * Nout + col] = v;
        }
    }
}

// ---------------- fused GATv2 edge + online segment-softmax + aggregate ----------------
// One wave per dst node. xl/xr layout: [N, 4 heads, 64 ch]; lane = channel.

__global__ __launch_bounds__(256) void gat_kernel(
    const float* __restrict__ xl, const float* __restrict__ xr,
    const float* __restrict__ att,
    const int* __restrict__ off, const int* __restrict__ srcs,
    float* __restrict__ conv, int N) {
    int lane = threadIdx.x & 63;
    int wid = blockIdx.x * 4 + (threadIdx.x >> 6);
    if (wid >= N) return;
    int n = __builtin_amdgcn_readfirstlane(wid);

    float xrv[4], attv[4], m[4], d[4], acc[4];
#pragma unroll
    for (int h = 0; h < 4; h++) {
        xrv[h] = xr[(size_t)n * 256 + h * 64 + lane];
        attv[h] = att[h * 64 + lane];
        m[h] = -INFINITY;
        d[h] = 0.f;
        acc[h] = 0.f;
    }

    int kb = off[n], ke = off[n + 1];
    for (int k = kb; k < ke; k++) {
        int s = srcs[k];
        const float* xp = xl + (size_t)s * 256 + lane;
        float xlv[4], e[4];
#pragma unroll
        for (int h = 0; h < 4; h++) xlv[h] = xp[h * 64];
#pragma unroll
        for (int h = 0; h < 4; h++) {
            float mm = xlv[h] + xrv[h];
            mm = (mm > 0.f) ? mm : 0.2f * mm;  // leaky_relu 0.2
            e[h] = mm * attv[h];
        }
        // 64-lane butterfly sum per head -> e[h] = attention logit
#pragma unroll
        for (int sft = 1; sft < 64; sft <<= 1) {
#pragma unroll
            for (int h = 0; h < 4; h++) e[h] += __shfl_xor(e[h], sft, 64);
        }
        // online softmax update
#pragma unroll
        for (int h = 0; h < 4; h++) {
            float nm = fmaxf(m[h], e[h]);
            float sc = expf(m[h] - nm);  // m=-inf first iter -> 0
            float w = expf(e[h] - nm);
            d[h] = d[h] * sc + w;
            acc[h] = acc[h] * sc + w * xlv[h];
            m[h] = nm;
        }
    }
#pragma unroll
    for (int h = 0; h < 4; h++) {
        size_t o = (size_t)n * 256 + h * 64 + lane;
        conv[o] += acc[h] / (d[h] + 1e-16f);  // sequential relation launches: no race
    }
}

// ---------------- misc elementwise ----------------

__global__ __launch_bounds__(256) void init_conv_kernel(const float* __restrict__ b,
                                                        float* __restrict__ conv, int N) {
    int idx = blockIdx.x * 256 + threadIdx.x;
    if (idx >= N * 256) return;
    int j = idx & 255;
    conv[idx] = b[j] + b[256 + j] + b[512 + j] + b[768 + j] + b[1024 + j];
}

__global__ __launch_bounds__(256) void relu_kernel(float* __restrict__ p, int total) {
    int idx = blockIdx.x * 256 + threadIdx.x;
    if (idx < total) p[idx] = fmaxf(p[idx], 0.f);
}

// out[n,0:3] = hmid[n,:] @ W2[128,3] + b2 — one wave per node
__global__ __launch_bounds__(256) void head_kernel(const float* __restrict__ hm,
                                                   const float* __restrict__ W2,
                                                   const float* __restrict__ b2,
                                                   float* __restrict__ out, int N) {
    int lane = threadIdx.x & 63;
    int wid = blockIdx.x * 4 + (threadIdx.x >> 6);
    if (wid >= N) return;
    int n = __builtin_amdgcn_readfirstlane(wid);
    float a0 = hm[(size_t)n * 128 + lane];
    float a1 = hm[(size_t)n * 128 + 64 + lane];
    float s0 = a0 * W2[lane * 3 + 0] + a1 * W2[(64 + lane) * 3 + 0];
    float s1 = a0 * W2[lane * 3 + 1] + a1 * W2[(64 + lane) * 3 + 1];
    float s2 = a0 * W2[lane * 3 + 2] + a1 * W2[(64 + lane) * 3 + 2];
#pragma unroll
    for (int sft = 1; sft < 64; sft <<= 1) {
        s0 += __shfl_xor(s0, sft, 64);
        s1 += __shfl_xor(s1, sft, 64);
        s2 += __shfl_xor(s2, sft, 64);
    }
    if (lane == 0) {
        out[(size_t)n * 3 + 0] = s0 + b2[0];
        out[(size_t)n * 3 + 1] = s1 + b2[1];
        out[(size_t)n * 3 + 2] = s2 + b2[2];
    }
}

// ---------------- launch ----------------

extern "C" void kernel_launch(void* const* d_in, const int* in_sizes, int n_in,
                              void* d_out, int out_size, void* d_ws, size_t ws_size,
                              hipStream_t stream) {
    const float* x    = (const float*)d_in[0];
    const int* date   = (const int*)d_in[1];
    const int* ei     = (const int*)d_in[2];
    const float* pW   = (const float*)d_in[3];
    const float* pb   = (const float*)d_in[4];
    const float* Wl0  = (const float*)d_in[5];
    const float* Wr0  = (const float*)d_in[6];
    const float* att0 = (const float*)d_in[7];
    const float* b0   = (const float*)d_in[8];
    const float* Wl1  = (const float*)d_in[9];
    const float* Wr1  = (const float*)d_in[10];
    const float* att1 = (const float*)d_in[11];
    const float* b1   = (const float*)d_in[12];
    // d_in[13..15] = aggW/aggb/agga — rel_agg is identity (h_rel broadcast), skipped
    const float* outW1 = (const float*)d_in[16];
    const float* outb1 = (const float*)d_in[17];
    const float* outW2 = (const float*)d_in[18];
    const float* outb2 = (const float*)d_in[19];
    float* out = (float*)d_out;

    int N = in_sizes[0] / 64;
    int E = in_sizes[2] / 10;

    char* ws = (char*)d_ws;
    size_t o = 0;
    auto alloc = [&](size_t bytes) -> char* {
        char* p = ws + o;
        o += (bytes + 255) & ~(size_t)255;
        return p;
    };
    int* cur    = (int*)alloc((size_t)5 * N * 4);
    int* csrOff = (int*)alloc((size_t)5 * (N + 1) * 4);
    int* csrSrc = (int*)alloc((size_t)5 * E * 4);
    float* h0   = (float*)alloc((size_t)N * 112 * 4);
    float* bufA = (float*)alloc((size_t)N * 256 * 4);
    float* bufB = (float*)alloc((size_t)N * 256 * 4);
    float* xl   = (float*)alloc((size_t)N * 256 * 4);
    float* xr   = (float*)alloc((size_t)N * 256 * 4);
    float* hmid = (float*)alloc((size_t)N * 128 * 4);
    (void)ws_size;

    int totE = 5 * E;

    // CSR by dst, per relation (edge topology reused by pearl + both layers)
    hipMemsetAsync(cur, 0, (size_t)5 * N * 4, stream);
    count_kernel<<<(totE + 255) / 256, 256, 0, stream>>>(ei, cur, N, E);
    scan_kernel<<<5, 1024, 0, stream>>>(cur, csrOff, N);
    hipMemsetAsync(cur, 0, (size_t)5 * N * 4, stream);
    scatter_kernel<<<(totE + 255) / 256, 256, 0, stream>>>(ei, csrOff, cur, csrSrc, N, E);

    // pearl PE + time PE + concat
    pearl_h0_kernel<<<(N + 3) / 4, 256, 0, stream>>>(x, date, csrOff, csrSrc, pW, pb, h0, N, E);

    dim3 gemmGrid((N + 63) / 64, 4, 2);
    int ecount = N * 256;

    // ----- layer 0 (K=112) -----
    init_conv_kernel<<<(ecount + 255) / 256, 256, 0, stream>>>(b0, bufA, N);
    for (int r = 0; r < 5; r++) {
        gemm_dual<<<gemmGrid, 256, 0, stream>>>(h0, Wl0 + (size_t)r * 112 * 256, xl,
                                                Wr0 + (size_t)r * 112 * 256, xr,
                                                N, 112, 256, nullptr, 0);
        gat_kernel<<<(N + 3) / 4, 256, 0, stream>>>(xl, xr, att0 + (size_t)r * 256,
                                                    csrOff + (size_t)r * (N + 1),
                                                    csrSrc + (size_t)r * E, bufA, N);
    }
    relu_kernel<<<(ecount + 255) / 256, 256, 0, stream>>>(bufA, ecount);

    // ----- layer 1 (K=256) -----
    init_conv_kernel<<<(ecount + 255) / 256, 256, 0, stream>>>(b1, bufB, N);
    for (int r = 0; r < 5; r++) {
        gemm_dual<<<gemmGrid, 256, 0, stream>>>(bufA, Wl1 + (size_t)r * 256 * 256, xl,
                                                Wr1 + (size_t)r * 256 * 256, xr,
                                                N, 256, 256, nullptr, 0);
        gat_kernel<<<(N + 3) / 4, 256, 0, stream>>>(xl, xr, att1 + (size_t)r * 256,
                                                    csrOff + (size_t)r * (N + 1),
                                                    csrSrc + (size_t)r * E, bufB, N);
    }
    relu_kernel<<<(ecount + 255) / 256, 256, 0, stream>>>(bufB, ecount);

    // ----- MLP head -----
    dim3 headGrid((N + 63) / 64, 2, 1);
    gemm_dual<<<headGrid, 256, 0, stream>>>(bufB, outW1, hmid, outW1, hmid,
                                            N, 256, 128, outb1, 1);
    head_kernel<<<(N + 3) / 4, 256, 0, stream>>>(hmid, outW2, outb2, out, N);
}

// Round 2
// 1600.133 us; speedup vs baseline: 1.3580x; 1.3580x over previous
//
#include <hip/hip_runtime.h>
#include <math.h>

// ---------------- CSR build ----------------

__global__ __launch_bounds__(256) void count_kernel(const int* __restrict__ ei,
                                                    int* __restrict__ cnt, int N, int E) {
    int idx = blockIdx.x * 256 + threadIdx.x;
    if (idx >= 5 * E) return;
    int r = idx / E;
    int e = idx - r * E;
    int dst = ei[(size_t)r * 2 * E + E + e];
    atomicAdd(&cnt[r * N + dst], 1);
}

__global__ __launch_bounds__(1024) void scan_kernel(const int* __restrict__ cnt,
                                                    int* __restrict__ off, int N) {
    int r = blockIdx.x, t = threadIdx.x;
    __shared__ int sd[1024];
    __shared__ int run;
    if (t == 0) run = 0;
    __syncthreads();
    for (int base = 0; base < N; base += 1024) {
        int v = (base + t < N) ? cnt[r * N + base + t] : 0;
        sd[t] = v;
        __syncthreads();
        for (int s = 1; s < 1024; s <<= 1) {
            int add = (t >= s) ? sd[t - s] : 0;
            __syncthreads();
            sd[t] += add;
            __syncthreads();
        }
        if (base + t < N) off[(size_t)r * (N + 1) + base + t] = run + sd[t] - v;
        __syncthreads();
        if (t == 1023) run += sd[1023];
        __syncthreads();
    }
    if (t == 0) off[(size_t)r * (N + 1) + N] = run;
}

__global__ __launch_bounds__(256) void scatter_kernel(const int* __restrict__ ei,
                                                      const int* __restrict__ off,
                                                      int* __restrict__ cur,
                                                      int* __restrict__ srcs, int N, int E) {
    int idx = blockIdx.x * 256 + threadIdx.x;
    if (idx >= 5 * E) return;
    int r = idx / E;
    int e = idx - r * E;
    int src = ei[(size_t)r * 2 * E + e];
    int dst = ei[(size_t)r * 2 * E + E + e];
    int pos = atomicAdd(&cur[r * N + dst], 1);
    srcs[(size_t)r * E + off[(size_t)r * (N + 1) + dst] + pos] = src;
}

// ---------------- PEARL PE + time PE + concat -> h0 [N,112] ----------------

__global__ __launch_bounds__(256) void pearl_h0_kernel(
    const float* __restrict__ x, const int* __restrict__ date,
    const int* __restrict__ off, const int* __restrict__ srcs,
    const float* __restrict__ pW, const float* __restrict__ pb,
    float* __restrict__ h0, int N, int E) {
    int lane = threadIdx.x & 63;
    int wid = blockIdx.x * 4 + (threadIdx.x >> 6);
    if (wid >= N) return;
    int n = __builtin_amdgcn_readfirstlane(wid);

    float acc = 0.f;
    int deg = 0;
    // unroll-by-4 gather: 4 independent row loads in flight (indices are wave-uniform)
    for (int r = 0; r < 5; r++) {
        int kb = off[(size_t)r * (N + 1) + n];
        int ke = off[(size_t)r * (N + 1) + n + 1];
        deg += ke - kb;
        const int* sp = srcs + (size_t)r * E;
        int k = kb;
        for (; k + 4 <= ke; k += 4) {
            int i0 = sp[k], i1 = sp[k + 1], i2 = sp[k + 2], i3 = sp[k + 3];
            float a0 = x[(size_t)i0 * 64 + lane];
            float a1 = x[(size_t)i1 * 64 + lane];
            float a2 = x[(size_t)i2 * 64 + lane];
            float a3 = x[(size_t)i3 * 64 + lane];
            acc += (a0 + a1) + (a2 + a3);
        }
        for (; k < ke; k++) acc += x[(size_t)sp[k] * 64 + lane];
    }
    float an = acc / fmaxf((float)deg, 1.0f);

    // pe[j] = tanh(b[j] + sum_c agg[c]*W[c,j]) via shuffle broadcast of agg
    float s = (lane < 32) ? pb[lane] : 0.f;
#pragma unroll 8
    for (int c = 0; c < 64; c++) {
        float av = __shfl(an, c, 64);
        if (lane < 32) s = fmaf(av, pW[c * 32 + lane], s);
    }

    // writes: [x(64) | pe(32) | tpe(16)]
    h0[(size_t)n * 112 + lane] = x[(size_t)n * 64 + lane];
    if (lane < 32) h0[(size_t)n * 112 + 64 + lane] = tanhf(s);
    if (lane < 16) {
        float t = (float)date[n] / 10000.0f;
        int i = lane & 7;
        float dv = expf((float)(2 * i) * (-0.57564627324851148f));
        float arg = t * dv;
        h0[(size_t)n * 112 + 96 + lane] = (lane < 8) ? sinf(arg) : cosf(arg);
    }
}

// ---------------- fp32 tiled GEMM: C = A[M,K] @ B[K,Nout] (+bias,relu) ----------------

__global__ __launch_bounds__(256) void gemm_dual(
    const float* __restrict__ A,
    const float* __restrict__ B0, float* __restrict__ C0,
    const float* __restrict__ B1, float* __restrict__ C1,
    int M, int K, int Nout,
    const float* __restrict__ bias, int do_relu) {
    const float* B = (blockIdx.z == 0) ? B0 : B1;
    float* C = (blockIdx.z == 0) ? C0 : C1;
    __shared__ float As[16][68];
    __shared__ float Bs[16][64];
    int tid = threadIdx.x;
    int row0 = blockIdx.x * 64, col0 = blockIdx.y * 64;
    int ty4 = (tid >> 4) << 2, tx4 = (tid & 15) << 2;
    float acc[4][4] = {};

    for (int kt = 0; kt < K; kt += 16) {
#pragma unroll
        for (int i = 0; i < 4; i++) {
            int lin = tid + i * 256;
            int m = lin >> 4, k = lin & 15;
            int row = row0 + m;
            As[k][m] = (row < M) ? A[(size_t)row * K + kt + k] : 0.f;
        }
#pragma unroll
        for (int i = 0; i < 4; i++) {
            int lin = tid + i * 256;
            int k = lin >> 6, c = lin & 63;
            Bs[k][c] = B[(size_t)(kt + k) * Nout + col0 + c];
        }
        __syncthreads();
#pragma unroll
        for (int kk = 0; kk < 16; kk++) {
            float4 a = *(const float4*)&As[kk][ty4];
            float4 b = *(const float4*)&Bs[kk][tx4];
            float av[4] = {a.x, a.y, a.z, a.w};
            float bv[4] = {b.x, b.y, b.z, b.w};
#pragma unroll
            for (int i = 0; i < 4; i++)
#pragma unroll
                for (int j = 0; j < 4; j++)
                    acc[i][j] = fmaf(av[i], bv[j], acc[i][j]);
        }
        __syncthreads();
    }

#pragma unroll
    for (int i = 0; i < 4; i++) {
        int row = row0 + ty4 + i;
        if (row >= M) continue;
#pragma unroll
        for (int j = 0; j < 4; j++) {
            int col = col0 + tx4 + j;
            float v = acc[i][j];
            if (bias) v += bias[col];
            if (do_relu) v = fmaxf(v, 0.f);
            C[(size_t)row * Nout + col] = v;
        }
    }
}

// ---------------- fused GATv2 edge + online segment-softmax + aggregate ----------------
// One wave per dst node. Lane layout: lane = h*16 + c; lane owns channels
// h*64 + c*4 + {0..3}  ->  xl gather is ONE float4 load; per-head dot reduces
// over 16 lanes (4 shuffles); each lane keeps only its own head's (m,d) state.

__global__ __launch_bounds__(256) void gat_kernel(
    const float* __restrict__ xl, const float* __restrict__ xr,
    const float* __restrict__ att,
    const int* __restrict__ off, const int* __restrict__ srcs,
    float* __restrict__ conv, int N) {
    int lane = threadIdx.x & 63;
    int wid = blockIdx.x * 4 + (threadIdx.x >> 6);
    if (wid >= N) return;
    int n = __builtin_amdgcn_readfirstlane(wid);

    int chanOff = ((lane >> 4) << 6) + ((lane & 15) << 2);  // h*64 + c*4

    float4 xrv = *(const float4*)(xr + (size_t)n * 256 + chanOff);
    float4 attv = *(const float4*)(att + chanOff);
    float m = -INFINITY, d = 0.f;
    float ax = 0.f, ay = 0.f, az = 0.f, aw = 0.f;

    int kb = off[n], ke = off[n + 1];
    if (kb < ke) {
        int kl = ke - 1;
        int s0 = srcs[kb];
        int s1 = srcs[(kb + 1 <= kl) ? kb + 1 : kl];
        float4 xlv = *(const float4*)(xl + (size_t)s0 * 256 + chanOff);
        for (int k = kb; k < ke; k++) {
            // prefetch next row + next-next index (breaks load-load chain)
            float4 nxt = *(const float4*)(xl + (size_t)s1 * 256 + chanOff);
            int s2 = srcs[(k + 2 <= kl) ? k + 2 : kl];

            // partial dot: sum_j leaky(xl+xr)*att over this lane's 4 channels
            float t0 = xlv.x + xrv.x; t0 = (t0 > 0.f) ? t0 : 0.2f * t0;
            float t1 = xlv.y + xrv.y; t1 = (t1 > 0.f) ? t1 : 0.2f * t1;
            float t2 = xlv.z + xrv.z; t2 = (t2 > 0.f) ? t2 : 0.2f * t2;
            float t3 = xlv.w + xrv.w; t3 = (t3 > 0.f) ? t3 : 0.2f * t3;
            float p = t0 * attv.x;
            p = fmaf(t1, attv.y, p);
            p = fmaf(t2, attv.z, p);
            p = fmaf(t3, attv.w, p);
            // reduce over the 16 lanes of this head
            p += __shfl_xor(p, 1, 64);
            p += __shfl_xor(p, 2, 64);
            p += __shfl_xor(p, 4, 64);
            p += __shfl_xor(p, 8, 64);

            // online softmax (this head only)
            float nm = fmaxf(m, p);
            float sc = __expf(m - nm);   // m=-inf first iter -> 0
            float w = __expf(p - nm);
            d = fmaf(d, sc, w);
            ax = fmaf(ax, sc, w * xlv.x);
            ay = fmaf(ay, sc, w * xlv.y);
            az = fmaf(az, sc, w * xlv.z);
            aw = fmaf(aw, sc, w * xlv.w);
            m = nm;

            xlv = nxt;
            s1 = s2;
        }
    }

    float inv = 1.0f / (d + 1e-16f);
    float* cp = conv + (size_t)n * 256 + chanOff;
    float4 cv = *(float4*)cp;
    cv.x += ax * inv;
    cv.y += ay * inv;
    cv.z += az * inv;
    cv.w += aw * inv;
    *(float4*)cp = cv;  // sequential relation launches: no race
}

// ---------------- misc elementwise ----------------

__global__ __launch_bounds__(256) void init_conv_kernel(const float* __restrict__ b,
                                                        float* __restrict__ conv, int N) {
    int idx = blockIdx.x * 256 + threadIdx.x;
    if (idx >= N * 256) return;
    int j = idx & 255;
    conv[idx] = b[j] + b[256 + j] + b[512 + j] + b[768 + j] + b[1024 + j];
}

__global__ __launch_bounds__(256) void relu_kernel(float* __restrict__ p, int total) {
    int idx = blockIdx.x * 256 + threadIdx.x;
    if (idx < total) p[idx] = fmaxf(p[idx], 0.f);
}

__global__ __launch_bounds__(256) void head_kernel(const float* __restrict__ hm,
                                                   const float* __restrict__ W2,
                                                   const float* __restrict__ b2,
                                                   float* __restrict__ out, int N) {
    int lane = threadIdx.x & 63;
    int wid = blockIdx.x * 4 + (threadIdx.x >> 6);
    if (wid >= N) return;
    int n = __builtin_amdgcn_readfirstlane(wid);
    float a0 = hm[(size_t)n * 128 + lane];
    float a1 = hm[(size_t)n * 128 + 64 + lane];
    float s0 = a0 * W2[lane * 3 + 0] + a1 * W2[(64 + lane) * 3 + 0];
    float s1 = a0 * W2[lane * 3 + 1] + a1 * W2[(64 + lane) * 3 + 1];
    float s2 = a0 * W2[lane * 3 + 2] + a1 * W2[(64 + lane) * 3 + 2];
#pragma unroll
    for (int sft = 1; sft < 64; sft <<= 1) {
        s0 += __shfl_xor(s0, sft, 64);
        s1 += __shfl_xor(s1, sft, 64);
        s2 += __shfl_xor(s2, sft, 64);
    }
    if (lane == 0) {
        out[(size_t)n * 3 + 0] = s0 + b2[0];
        out[(size_t)n * 3 + 1] = s1 + b2[1];
        out[(size_t)n * 3 + 2] = s2 + b2[2];
    }
}

// ---------------- launch ----------------

extern "C" void kernel_launch(void* const* d_in, const int* in_sizes, int n_in,
                              void* d_out, int out_size, void* d_ws, size_t ws_size,
                              hipStream_t stream) {
    const float* x    = (const float*)d_in[0];
    const int* date   = (const int*)d_in[1];
    const int* ei     = (const int*)d_in[2];
    const float* pW   = (const float*)d_in[3];
    const float* pb   = (const float*)d_in[4];
    const float* Wl0  = (const float*)d_in[5];
    const float* Wr0  = (const float*)d_in[6];
    const float* att0 = (const float*)d_in[7];
    const float* b0   = (const float*)d_in[8];
    const float* Wl1  = (const float*)d_in[9];
    const float* Wr1  = (const float*)d_in[10];
    const float* att1 = (const float*)d_in[11];
    const float* b1   = (const float*)d_in[12];
    // d_in[13..15] = aggW/aggb/agga — rel_agg is identity (h_rel broadcast), skipped
    const float* outW1 = (const float*)d_in[16];
    const float* outb1 = (const float*)d_in[17];
    const float* outW2 = (const float*)d_in[18];
    const float* outb2 = (const float*)d_in[19];
    float* out = (float*)d_out;

    int N = in_sizes[0] / 64;
    int E = in_sizes[2] / 10;

    char* ws = (char*)d_ws;
    size_t o = 0;
    auto alloc = [&](size_t bytes) -> char* {
        char* p = ws + o;
        o += (bytes + 255) & ~(size_t)255;
        return p;
    };
    int* cur    = (int*)alloc((size_t)5 * N * 4);
    int* csrOff = (int*)alloc((size_t)5 * (N + 1) * 4);
    int* csrSrc = (int*)alloc((size_t)5 * E * 4);
    float* h0   = (float*)alloc((size_t)N * 112 * 4);
    float* bufA = (float*)alloc((size_t)N * 256 * 4);
    float* bufB = (float*)alloc((size_t)N * 256 * 4);
    float* xl   = (float*)alloc((size_t)N * 256 * 4);
    float* xr   = (float*)alloc((size_t)N * 256 * 4);
    float* hmid = (float*)alloc((size_t)N * 128 * 4);
    (void)ws_size;

    int totE = 5 * E;

    // CSR by dst, per relation (edge topology reused by pearl + both layers)
    hipMemsetAsync(cur, 0, (size_t)5 * N * 4, stream);
    count_kernel<<<(totE + 255) / 256, 256, 0, stream>>>(ei, cur, N, E);
    scan_kernel<<<5, 1024, 0, stream>>>(cur, csrOff, N);
    hipMemsetAsync(cur, 0, (size_t)5 * N * 4, stream);
    scatter_kernel<<<(totE + 255) / 256, 256, 0, stream>>>(ei, csrOff, cur, csrSrc, N, E);

    // pearl PE + time PE + concat
    pearl_h0_kernel<<<(N + 3) / 4, 256, 0, stream>>>(x, date, csrOff, csrSrc, pW, pb, h0, N, E);

    dim3 gemmGrid((N + 63) / 64, 4, 2);
    int ecount = N * 256;

    // ----- layer 0 (K=112) -----
    init_conv_kernel<<<(ecount + 255) / 256, 256, 0, stream>>>(b0, bufA, N);
    for (int r = 0; r < 5; r++) {
        gemm_dual<<<gemmGrid, 256, 0, stream>>>(h0, Wl0 + (size_t)r * 112 * 256, xl,
                                                Wr0 + (size_t)r * 112 * 256, xr,
                                                N, 112, 256, nullptr, 0);
        gat_kernel<<<(N + 3) / 4, 256, 0, stream>>>(xl, xr, att0 + (size_t)r * 256,
                                                    csrOff + (size_t)r * (N + 1),
                                                    csrSrc + (size_t)r * E, bufA, N);
    }
    relu_kernel<<<(ecount + 255) / 256, 256, 0, stream>>>(bufA, ecount);

    // ----- layer 1 (K=256) -----
    init_conv_kernel<<<(ecount + 255) / 256, 256, 0, stream>>>(b1, bufB, N);
    for (int r = 0; r < 5; r++) {
        gemm_dual<<<gemmGrid, 256, 0, stream>>>(bufA, Wl1 + (size_t)r * 256 * 256, xl,
                                                Wr1 + (size_t)r * 256 * 256, xr,
                                                N, 256, 256, nullptr, 0);
        gat_kernel<<<(N + 3) / 4, 256, 0, stream>>>(xl, xr, att1 + (size_t)r * 256,
                                                    csrOff + (size_t)r * (N + 1),
                                                    csrSrc + (size_t)r * E, bufB, N);
    }
    relu_kernel<<<(ecount + 255) / 256, 256, 0, stream>>>(bufB, ecount);

    // ----- MLP head -----
    dim3 headGrid((N + 63) / 64, 2, 1);
    gemm_dual<<<headGrid, 256, 0, stream>>>(bufB, outW1, hmid, outW1, hmid,
                                            N, 256, 128, outb1, 1);
    head_kernel<<<(N + 3) / 4, 256, 0, stream>>>(hmid, outW2, outb2, out, N);
}

// Round 3
// 1229.393 us; speedup vs baseline: 1.7675x; 1.3016x over previous
//
#include <hip/hip_runtime.h>
#include <math.h>

typedef __bf16 bf16x8 __attribute__((ext_vector_type(8)));
typedef float f32x4 __attribute__((ext_vector_type(4)));

#define GLD16(src, dst)                                                        \
    __builtin_amdgcn_global_load_lds(                                          \
        (const __attribute__((address_space(1))) void*)(src),                  \
        (__attribute__((address_space(3))) void*)(dst), 16, 0, 0)

// ---------------- CSR build ----------------

__global__ __launch_bounds__(256) void count_kernel(const int* __restrict__ ei,
                                                    int* __restrict__ cnt, int N, int E) {
    int idx = blockIdx.x * 256 + threadIdx.x;
    if (idx >= 5 * E) return;
    int r = idx / E;
    int e = idx - r * E;
    int dst = ei[(size_t)r * 2 * E + E + e];
    atomicAdd(&cnt[r * N + dst], 1);
}

__global__ __launch_bounds__(1024) void scan_kernel(const int* __restrict__ cnt,
                                                    int* __restrict__ off, int N) {
    int r = blockIdx.x, t = threadIdx.x;
    __shared__ int sd[1024];
    __shared__ int run;
    if (t == 0) run = 0;
    __syncthreads();
    for (int base = 0; base < N; base += 1024) {
        int v = (base + t < N) ? cnt[r * N + base + t] : 0;
        sd[t] = v;
        __syncthreads();
        for (int s = 1; s < 1024; s <<= 1) {
            int add = (t >= s) ? sd[t - s] : 0;
            __syncthreads();
            sd[t] += add;
            __syncthreads();
        }
        if (base + t < N) off[(size_t)r * (N + 1) + base + t] = run + sd[t] - v;
        __syncthreads();
        if (t == 1023) run += sd[1023];
        __syncthreads();
    }
    if (t == 0) off[(size_t)r * (N + 1) + N] = run;
}

__global__ __launch_bounds__(256) void scatter_kernel(const int* __restrict__ ei,
                                                      const int* __restrict__ off,
                                                      int* __restrict__ cur,
                                                      int* __restrict__ srcs, int N, int E) {
    int idx = blockIdx.x * 256 + threadIdx.x;
    if (idx >= 5 * E) return;
    int r = idx / E;
    int e = idx - r * E;
    int src = ei[(size_t)r * 2 * E + e];
    int dst = ei[(size_t)r * 2 * E + E + e];
    int pos = atomicAdd(&cur[r * N + dst], 1);
    srcs[(size_t)r * E + off[(size_t)r * (N + 1) + dst] + pos] = src;
}

// ---------------- PEARL PE + time PE + concat -> h0 [N,112] ----------------

__global__ __launch_bounds__(256) void pearl_h0_kernel(
    const float* __restrict__ x, const int* __restrict__ date,
    const int* __restrict__ off, const int* __restrict__ srcs,
    const float* __restrict__ pW, const float* __restrict__ pb,
    float* __restrict__ h0, int N, int E) {
    int lane = threadIdx.x & 63;
    int wid = blockIdx.x * 4 + (threadIdx.x >> 6);
    if (wid >= N) return;
    int n = __builtin_amdgcn_readfirstlane(wid);

    float acc = 0.f;
    int deg = 0;
    for (int r = 0; r < 5; r++) {
        int kb = off[(size_t)r * (N + 1) + n];
        int ke = off[(size_t)r * (N + 1) + n + 1];
        deg += ke - kb;
        const int* sp = srcs + (size_t)r * E;
        int k = kb;
        for (; k + 4 <= ke; k += 4) {
            int i0 = sp[k], i1 = sp[k + 1], i2 = sp[k + 2], i3 = sp[k + 3];
            float a0 = x[(size_t)i0 * 64 + lane];
            float a1 = x[(size_t)i1 * 64 + lane];
            float a2 = x[(size_t)i2 * 64 + lane];
            float a3 = x[(size_t)i3 * 64 + lane];
            acc += (a0 + a1) + (a2 + a3);
        }
        for (; k < ke; k++) acc += x[(size_t)sp[k] * 64 + lane];
    }
    float an = acc / fmaxf((float)deg, 1.0f);

    float s = (lane < 32) ? pb[lane] : 0.f;
#pragma unroll 8
    for (int c = 0; c < 64; c++) {
        float av = __shfl(an, c, 64);
        if (lane < 32) s = fmaf(av, pW[c * 32 + lane], s);
    }

    h0[(size_t)n * 112 + lane] = x[(size_t)n * 64 + lane];
    if (lane < 32) h0[(size_t)n * 112 + 64 + lane] = tanhf(s);
    if (lane < 16) {
        float t = (float)date[n] / 10000.0f;
        int i = lane & 7;
        float dv = expf((float)(2 * i) * (-0.57564627324851148f));
        float arg = t * dv;
        h0[(size_t)n * 112 + 96 + lane] = (lane < 8) ? sinf(arg) : cosf(arg);
    }
}

// ---------------- pack A [M,K] fp32 -> hi/lo bf16, MFMA-fragment-major ----------------
// layout: [mt = m>>4][kt = k>>5][lane = (kg<<4)|mr][8]  (kg = (k>>3)&3, mr = m&15)

__global__ __launch_bounds__(256) void pack_a_kernel(
    const float* __restrict__ A, __bf16* __restrict__ Ah, __bf16* __restrict__ Al,
    int M, int K, int Mp, int KT) {
    int KG = KT * 4;
    int idx = blockIdx.x * 256 + threadIdx.x;
    if (idx >= Mp * KG) return;
    int m = idx / KG, kgg = idx - m * KG;
    int kt = kgg >> 2, kg = kgg & 3;
    int k0 = kt * 32 + kg * 8;
    int mt = m >> 4, mr = m & 15;
    size_t out = (((size_t)mt * KT + kt) * 64 + kg * 16 + mr) * 8;
    bf16x8 hv, lv;
#pragma unroll
    for (int j = 0; j < 8; j++) {
        int k = k0 + j;
        float v = (m < M && k < K) ? A[(size_t)m * K + k] : 0.f;
        __bf16 h = (__bf16)v;
        hv[j] = h;
        lv[j] = (__bf16)(v - (float)h);
    }
    *(bf16x8*)(Ah + out) = hv;
    *(bf16x8*)(Al + out) = lv;
}

// ---------------- pack all weights (21 tensors, grid.y selects) ----------------
// layout: [nt = n>>4][kt][lane = (kg<<4)|nr][8]

__global__ __launch_bounds__(256) void pack_w_kernel(
    const float* __restrict__ Wl0, const float* __restrict__ Wr0,
    const float* __restrict__ Wl1, const float* __restrict__ Wr1,
    const float* __restrict__ W1,
    __bf16* __restrict__ Wph, __bf16* __restrict__ Wpl) {
    const int S0 = 32768, S1 = 65536;
    int t = blockIdx.y;
    const float* W;
    int K, Nc, KT;
    size_t dst;
    if (t < 5)       { W = Wl0 + (size_t)t * 112 * 256;        K = 112; Nc = 256; KT = 4; dst = (size_t)t * S0; }
    else if (t < 10) { W = Wr0 + (size_t)(t - 5) * 112 * 256;  K = 112; Nc = 256; KT = 4; dst = 163840 + (size_t)(t - 5) * S0; }
    else if (t < 15) { W = Wl1 + (size_t)(t - 10) * 256 * 256; K = 256; Nc = 256; KT = 8; dst = 327680 + (size_t)(t - 10) * S1; }
    else if (t < 20) { W = Wr1 + (size_t)(t - 15) * 256 * 256; K = 256; Nc = 256; KT = 8; dst = 655360 + (size_t)(t - 15) * S1; }
    else             { W = W1;                                  K = 256; Nc = 128; KT = 8; dst = 983040; }
    int entries = (Nc / 16) * KT * 64;
    int idx = blockIdx.x * 256 + threadIdx.x;
    if (idx >= entries) return;
    int nt = idx / (KT * 64);
    int rem = idx - nt * (KT * 64);
    int kt = rem >> 6, lane = rem & 63;
    int kg = lane >> 4, nr = lane & 15;
    bf16x8 hv, lv;
#pragma unroll
    for (int j = 0; j < 8; j++) {
        int k = kt * 32 + kg * 8 + j;
        float v = (k < K) ? W[(size_t)k * Nc + nt * 16 + nr] : 0.f;
        __bf16 h = (__bf16)v;
        hv[j] = h;
        lv[j] = (__bf16)(v - (float)h);
    }
    *(bf16x8*)(Wph + dst + (size_t)idx * 8) = hv;
    *(bf16x8*)(Wpl + dst + (size_t)idx * 8) = lv;
}

// ---------------- split-bf16 MFMA GEMM: C = A@B, 3-pass (AhBh + AlBh + AhBl) ----------------
// 128x128 block tile, 4 waves (each 64x64 = 4x4 frags of 16x16x32), BK=32.
// blockIdx.z selects (B0,C0)/(B1,C1) dual output.

__global__ __launch_bounds__(256) void gemm_mfma(
    const __bf16* __restrict__ Ah, const __bf16* __restrict__ Al,
    const __bf16* __restrict__ Bh0, const __bf16* __restrict__ Bl0, float* __restrict__ C0,
    const __bf16* __restrict__ Bh1, const __bf16* __restrict__ Bl1, float* __restrict__ C1,
    int M, int Nout, int KT,
    const float* __restrict__ bias, int do_relu) {
    const __bf16* Bh = blockIdx.z ? Bh1 : Bh0;
    const __bf16* Bl = blockIdx.z ? Bl1 : Bl0;
    float* C = blockIdx.z ? C1 : C0;

    __shared__ __bf16 sAh[8 * 512], sAl[8 * 512], sBh[8 * 512], sBl[8 * 512];

    int tid = threadIdx.x, lane = tid & 63, w = tid >> 6;
    int wr = w >> 1, wc = w & 1;
    int bx = blockIdx.x, by = blockIdx.y;

    f32x4 acc[4][4] = {};

    for (int kt = 0; kt < KT; ++kt) {
        // stage: wave w loads tiles {2w, 2w+1} of A(h,l) and B(h,l); 1KB each, linear dest
        int tl = w * 2;
        size_t a0 = ((size_t)(bx * 8 + tl) * KT + kt) * 512 + lane * 8;
        size_t a1 = ((size_t)(bx * 8 + tl + 1) * KT + kt) * 512 + lane * 8;
        size_t b0 = ((size_t)(by * 8 + tl) * KT + kt) * 512 + lane * 8;
        size_t b1 = ((size_t)(by * 8 + tl + 1) * KT + kt) * 512 + lane * 8;
        GLD16(Ah + a0, sAh + tl * 512);
        GLD16(Ah + a1, sAh + (tl + 1) * 512);
        GLD16(Al + a0, sAl + tl * 512);
        GLD16(Al + a1, sAl + (tl + 1) * 512);
        GLD16(Bh + b0, sBh + tl * 512);
        GLD16(Bh + b1, sBh + (tl + 1) * 512);
        GLD16(Bl + b0, sBl + tl * 512);
        GLD16(Bl + b1, sBl + (tl + 1) * 512);
        __syncthreads();

        bf16x8 ah[4], al[4], bh[4], bl[4];
#pragma unroll
        for (int i = 0; i < 4; i++) {
            ah[i] = *(const bf16x8*)(sAh + (wr * 4 + i) * 512 + lane * 8);
            al[i] = *(const bf16x8*)(sAl + (wr * 4 + i) * 512 + lane * 8);
            bh[i] = *(const bf16x8*)(sBh + (wc * 4 + i) * 512 + lane * 8);
            bl[i] = *(const bf16x8*)(sBl + (wc * 4 + i) * 512 + lane * 8);
        }
#pragma unroll
        for (int i = 0; i < 4; i++)
#pragma unroll
            for (int j = 0; j < 4; j++) {
                acc[i][j] = __builtin_amdgcn_mfma_f32_16x16x32_bf16(ah[i], bh[j], acc[i][j], 0, 0, 0);
                acc[i][j] = __builtin_amdgcn_mfma_f32_16x16x32_bf16(al[i], bh[j], acc[i][j], 0, 0, 0);
                acc[i][j] = __builtin_amdgcn_mfma_f32_16x16x32_bf16(ah[i], bl[j], acc[i][j], 0, 0, 0);
            }
        __syncthreads();
    }

    // epilogue: D lane mapping col=lane&15, row=(lane>>4)*4+r  [m89-verified]
    int rb = bx * 128 + wr * 64, cb = by * 128 + wc * 64;
#pragma unroll
    for (int i = 0; i < 4; i++) {
#pragma unroll
        for (int j = 0; j < 4; j++) {
            int row0 = rb + i * 16 + (lane >> 4) * 4;
            int col = cb + j * 16 + (lane & 15);
            float bv = bias ? bias[col] : 0.f;
#pragma unroll
            for (int r = 0; r < 4; r++) {
                int row = row0 + r;
                if (row < M) {
                    float v = acc[i][j][r] + bv;
                    if (do_relu) v = fmaxf(v, 0.f);
                    C[(size_t)row * Nout + col] = v;
                }
            }
        }
    }
}

// ---------------- fused GATv2 edge + online segment-softmax + aggregate ----------------

__global__ __launch_bounds__(256) void gat_kernel(
    const float* __restrict__ xl, const float* __restrict__ xr,
    const float* __restrict__ att,
    const int* __restrict__ off, const int* __restrict__ srcs,
    float* __restrict__ conv, int N, int do_relu) {
    int lane = threadIdx.x & 63;
    int wid = blockIdx.x * 4 + (threadIdx.x >> 6);
    if (wid >= N) return;
    int n = __builtin_amdgcn_readfirstlane(wid);

    int chanOff = ((lane >> 4) << 6) + ((lane & 15) << 2);  // h*64 + c*4

    float4 xrv = *(const float4*)(xr + (size_t)n * 256 + chanOff);
    float4 attv = *(const float4*)(att + chanOff);
    float m = -INFINITY, d = 0.f;
    float ax = 0.f, ay = 0.f, az = 0.f, aw = 0.f;

    int kb = off[n], ke = off[n + 1];
    if (kb < ke) {
        int kl = ke - 1;
        int s0 = srcs[kb];
        int s1 = srcs[(kb + 1 <= kl) ? kb + 1 : kl];
        float4 xlv = *(const float4*)(xl + (size_t)s0 * 256 + chanOff);
        for (int k = kb; k < ke; k++) {
            float4 nxt = *(const float4*)(xl + (size_t)s1 * 256 + chanOff);
            int s2 = srcs[(k + 2 <= kl) ? k + 2 : kl];

            float t0 = xlv.x + xrv.x; t0 = (t0 > 0.f) ? t0 : 0.2f * t0;
            float t1 = xlv.y + xrv.y; t1 = (t1 > 0.f) ? t1 : 0.2f * t1;
            float t2 = xlv.z + xrv.z; t2 = (t2 > 0.f) ? t2 : 0.2f * t2;
            float t3 = xlv.w + xrv.w; t3 = (t3 > 0.f) ? t3 : 0.2f * t3;
            float p = t0 * attv.x;
            p = fmaf(t1, attv.y, p);
            p = fmaf(t2, attv.z, p);
            p = fmaf(t3, attv.w, p);
            p += __shfl_xor(p, 1, 64);
            p += __shfl_xor(p, 2, 64);
            p += __shfl_xor(p, 4, 64);
            p += __shfl_xor(p, 8, 64);

            float nm = fmaxf(m, p);
            float sc = __expf(m - nm);
            float wgt = __expf(p - nm);
            d = fmaf(d, sc, wgt);
            ax = fmaf(ax, sc, wgt * xlv.x);
            ay = fmaf(ay, sc, wgt * xlv.y);
            az = fmaf(az, sc, wgt * xlv.z);
            aw = fmaf(aw, sc, wgt * xlv.w);
            m = nm;

            xlv = nxt;
            s1 = s2;
        }
    }

    float inv = 1.0f / (d + 1e-16f);
    float* cp = conv + (size_t)n * 256 + chanOff;
    float4 cv = *(float4*)cp;
    cv.x += ax * inv;
    cv.y += ay * inv;
    cv.z += az * inv;
    cv.w += aw * inv;
    if (do_relu) {
        cv.x = fmaxf(cv.x, 0.f);
        cv.y = fmaxf(cv.y, 0.f);
        cv.z = fmaxf(cv.z, 0.f);
        cv.w = fmaxf(cv.w, 0.f);
    }
    *(float4*)cp = cv;
}

// ---------------- misc ----------------

__global__ __launch_bounds__(256) void init_conv_kernel(const float* __restrict__ b,
                                                        float* __restrict__ conv, int N) {
    int idx = blockIdx.x * 256 + threadIdx.x;
    if (idx >= N * 256) return;
    int j = idx & 255;
    conv[idx] = b[j] + b[256 + j] + b[512 + j] + b[768 + j] + b[1024 + j];
}

__global__ __launch_bounds__(256) void head_kernel(const float* __restrict__ hm,
                                                   const float* __restrict__ W2,
                                                   const float* __restrict__ b2,
                                                   float* __restrict__ out, int N) {
    int lane = threadIdx.x & 63;
    int wid = blockIdx.x * 4 + (threadIdx.x >> 6);
    if (wid >= N) return;
    int n = __builtin_amdgcn_readfirstlane(wid);
    float a0 = hm[(size_t)n * 128 + lane];
    float a1 = hm[(size_t)n * 128 + 64 + lane];
    float s0 = a0 * W2[lane * 3 + 0] + a1 * W2[(64 + lane) * 3 + 0];
    float s1 = a0 * W2[lane * 3 + 1] + a1 * W2[(64 + lane) * 3 + 1];
    float s2 = a0 * W2[lane * 3 + 2] + a1 * W2[(64 + lane) * 3 + 2];
#pragma unroll
    for (int sft = 1; sft < 64; sft <<= 1) {
        s0 += __shfl_xor(s0, sft, 64);
        s1 += __shfl_xor(s1, sft, 64);
        s2 += __shfl_xor(s2, sft, 64);
    }
    if (lane == 0) {
        out[(size_t)n * 3 + 0] = s0 + b2[0];
        out[(size_t)n * 3 + 1] = s1 + b2[1];
        out[(size_t)n * 3 + 2] = s2 + b2[2];
    }
}

// ---------------- launch ----------------

extern "C" void kernel_launch(void* const* d_in, const int* in_sizes, int n_in,
                              void* d_out, int out_size, void* d_ws, size_t ws_size,
                              hipStream_t stream) {
    const float* x    = (const float*)d_in[0];
    const int* date   = (const int*)d_in[1];
    const int* ei     = (const int*)d_in[2];
    const float* pW   = (const float*)d_in[3];
    const float* pb   = (const float*)d_in[4];
    const float* Wl0  = (const float*)d_in[5];
    const float* Wr0  = (const float*)d_in[6];
    const float* att0 = (const float*)d_in[7];
    const float* b0   = (const float*)d_in[8];
    const float* Wl1  = (const float*)d_in[9];
    const float* Wr1  = (const float*)d_in[10];
    const float* att1 = (const float*)d_in[11];
    const float* b1   = (const float*)d_in[12];
    // d_in[13..15] = aggW/aggb/agga — rel_agg is identity (h_rel broadcast), skipped
    const float* outW1 = (const float*)d_in[16];
    const float* outb1 = (const float*)d_in[17];
    const float* outW2 = (const float*)d_in[18];
    const float* outb2 = (const float*)d_in[19];
    float* out = (float*)d_out;

    int N = in_sizes[0] / 64;
    int E = in_sizes[2] / 10;
    int Mp = ((N + 127) / 128) * 128;
    int MT = Mp / 128;

    char* ws = (char*)d_ws;
    size_t o = 0;
    auto alloc = [&](size_t bytes) -> char* {
        char* p = ws + o;
        o += (bytes + 255) & ~(size_t)255;
        return p;
    };
    int* cur      = (int*)alloc((size_t)5 * N * 4);
    int* csrOff   = (int*)alloc((size_t)5 * (N + 1) * 4);
    int* csrSrc   = (int*)alloc((size_t)5 * E * 4);
    float* h0     = (float*)alloc((size_t)N * 112 * 4);
    float* bufA   = (float*)alloc((size_t)N * 256 * 4);
    float* bufB   = (float*)alloc((size_t)N * 256 * 4);
    float* xl     = (float*)alloc((size_t)N * 256 * 4);
    float* xr     = (float*)alloc((size_t)N * 256 * 4);
    __bf16* Aph   = (__bf16*)alloc((size_t)Mp * 256 * 2);
    __bf16* Apl   = (__bf16*)alloc((size_t)Mp * 256 * 2);
    __bf16* Wph   = (__bf16*)alloc((size_t)1015808 * 2);
    __bf16* Wpl   = (__bf16*)alloc((size_t)1015808 * 2);
    float* hmid   = xl;  // head GEMM output reuses xl (free after layer-1 GAT)
    (void)ws_size;

    const size_t S0 = 32768, S1 = 65536;
    const size_t oWl0 = 0, oWr0 = 163840, oWl1 = 327680, oWr1 = 655360, oW1 = 983040;

    int totE = 5 * E;

    // CSR by dst, per relation
    hipMemsetAsync(cur, 0, (size_t)5 * N * 4, stream);
    count_kernel<<<(totE + 255) / 256, 256, 0, stream>>>(ei, cur, N, E);
    scan_kernel<<<5, 1024, 0, stream>>>(cur, csrOff, N);
    hipMemsetAsync(cur, 0, (size_t)5 * N * 4, stream);
    scatter_kernel<<<(totE + 255) / 256, 256, 0, stream>>>(ei, csrOff, cur, csrSrc, N, E);

    // pearl PE + time PE + concat
    pearl_h0_kernel<<<(N + 3) / 4, 256, 0, stream>>>(x, date, csrOff, csrSrc, pW, pb, h0, N, E);

    // pack all weights (hi/lo split)
    pack_w_kernel<<<dim3(32, 21, 1), 256, 0, stream>>>(Wl0, Wr0, Wl1, Wr1, outW1, Wph, Wpl);

    int ecount = N * 256;
    dim3 gemmGrid(MT, 2, 2);

    // ----- layer 0 (K=112 -> Kp=128, KT=4) -----
    pack_a_kernel<<<(Mp * 16 + 255) / 256, 256, 0, stream>>>(h0, Aph, Apl, N, 112, Mp, 4);
    init_conv_kernel<<<(ecount + 255) / 256, 256, 0, stream>>>(b0, bufA, N);
    for (int r = 0; r < 5; r++) {
        gemm_mfma<<<gemmGrid, 256, 0, stream>>>(
            Aph, Apl,
            Wph + oWl0 + r * S0, Wpl + oWl0 + r * S0, xl,
            Wph + oWr0 + r * S0, Wpl + oWr0 + r * S0, xr,
            N, 256, 4, nullptr, 0);
        gat_kernel<<<(N + 3) / 4, 256, 0, stream>>>(xl, xr, att0 + (size_t)r * 256,
                                                    csrOff + (size_t)r * (N + 1),
                                                    csrSrc + (size_t)r * E, bufA, N, r == 4);
    }

    // ----- layer 1 (K=256, KT=8) -----
    pack_a_kernel<<<(Mp * 32 + 255) / 256, 256, 0, stream>>>(bufA, Aph, Apl, N, 256, Mp, 8);
    init_conv_kernel<<<(ecount + 255) / 256, 256, 0, stream>>>(b1, bufB, N);
    for (int r = 0; r < 5; r++) {
        gemm_mfma<<<gemmGrid, 256, 0, stream>>>(
            Aph, Apl,
            Wph + oWl1 + r * S1, Wpl + oWl1 + r * S1, xl,
            Wph + oWr1 + r * S1, Wpl + oWr1 + r * S1, xr,
            N, 256, 8, nullptr, 0);
        gat_kernel<<<(N + 3) / 4, 256, 0, stream>>>(xl, xr, att1 + (size_t)r * 256,
                                                    csrOff + (size_t)r * (N + 1),
                                                    csrSrc + (size_t)r * E, bufB, N, r == 4);
    }

    // ----- MLP head: hmid = relu(bufB @ outW1 + outb1) -----
    pack_a_kernel<<<(Mp * 32 + 255) / 256, 256, 0, stream>>>(bufB, Aph, Apl, N, 256, Mp, 8);
    dim3 headGrid(MT, 1, 1);
    gemm_mfma<<<headGrid, 256, 0, stream>>>(
        Aph, Apl,
        Wph + oW1, Wpl + oW1, hmid,
        Wph + oW1, Wpl + oW1, hmid,
        N, 128, 8, outb1, 1);
    head_kernel<<<(N + 3) / 4, 256, 0, stream>>>(hmid, outW2, outb2, out, N);
}

// Round 4
// 1175.735 us; speedup vs baseline: 1.8482x; 1.0456x over previous
//
#include <hip/hip_runtime.h>
#include <math.h>

typedef __bf16 bf16x8 __attribute__((ext_vector_type(8)));
typedef float f32x4 __attribute__((ext_vector_type(4)));

#define GLD16(src, dst)                                                        \
    __builtin_amdgcn_global_load_lds(                                          \
        (const __attribute__((address_space(1))) void*)(src),                  \
        (__attribute__((address_space(3))) void*)(dst), 16, 0, 0)

// ---------------- CSR build ----------------

__global__ __launch_bounds__(256) void count_kernel(const int* __restrict__ ei,
                                                    int* __restrict__ cnt, int N, int E) {
    int idx = blockIdx.x * 256 + threadIdx.x;
    if (idx >= 5 * E) return;
    int r = idx / E;
    int e = idx - r * E;
    int dst = ei[(size_t)r * 2 * E + E + e];
    atomicAdd(&cnt[r * N + dst], 1);
}

// 3-phase parallel scan: A) chunk-local exclusive scan, B) scan chunk sums, C) add back.
__global__ __launch_bounds__(256) void scanA_kernel(const int* __restrict__ cnt,
                                                    int* __restrict__ off,
                                                    int* __restrict__ csums, int N, int NC) {
    int r = blockIdx.y, c = blockIdx.x, t = threadIdx.x;
    int idx0 = c * 1024 + t * 4;
    int v0 = (idx0 + 0 < N) ? cnt[r * N + idx0 + 0] : 0;
    int v1 = (idx0 + 1 < N) ? cnt[r * N + idx0 + 1] : 0;
    int v2 = (idx0 + 2 < N) ? cnt[r * N + idx0 + 2] : 0;
    int v3 = (idx0 + 3 < N) ? cnt[r * N + idx0 + 3] : 0;
    int ts = v0 + v1 + v2 + v3;
    __shared__ int sd[256];
    sd[t] = ts;
    __syncthreads();
    for (int s = 1; s < 256; s <<= 1) {
        int add = (t >= s) ? sd[t - s] : 0;
        __syncthreads();
        sd[t] += add;
        __syncthreads();
    }
    int excl = sd[t] - ts;
    size_t base = (size_t)r * (N + 1);
    if (idx0 + 0 < N) off[base + idx0 + 0] = excl;
    if (idx0 + 1 < N) off[base + idx0 + 1] = excl + v0;
    if (idx0 + 2 < N) off[base + idx0 + 2] = excl + v0 + v1;
    if (idx0 + 3 < N) off[base + idx0 + 3] = excl + v0 + v1 + v2;
    if (t == 255) csums[r * NC + c] = sd[255];
}

__global__ __launch_bounds__(64) void scanB_kernel(int* __restrict__ csums,
                                                   int* __restrict__ off, int N, int NC) {
    int r = threadIdx.x;
    if (r < 5) {
        int run = 0;
        for (int c = 0; c < NC; c++) {
            int t = csums[r * NC + c];
            csums[r * NC + c] = run;
            run += t;
        }
        off[(size_t)r * (N + 1) + N] = run;
    }
}

__global__ __launch_bounds__(256) void scanC_kernel(int* __restrict__ off,
                                                    const int* __restrict__ csums,
                                                    int N, int NC) {
    int r = blockIdx.y, c = blockIdx.x, t = threadIdx.x;
    int add = csums[r * NC + c];
    int idx0 = c * 1024 + t * 4;
    size_t base = (size_t)r * (N + 1);
#pragma unroll
    for (int j = 0; j < 4; j++)
        if (idx0 + j < N) off[base + idx0 + j] += add;
}

__global__ __launch_bounds__(256) void scatter_kernel(const int* __restrict__ ei,
                                                      const int* __restrict__ off,
                                                      int* __restrict__ cur,
                                                      int* __restrict__ srcs, int N, int E) {
    int idx = blockIdx.x * 256 + threadIdx.x;
    if (idx >= 5 * E) return;
    int r = idx / E;
    int e = idx - r * E;
    int src = ei[(size_t)r * 2 * E + e];
    int dst = ei[(size_t)r * 2 * E + E + e];
    int pos = atomicAdd(&cur[r * N + dst], 1);
    srcs[(size_t)r * E + off[(size_t)r * (N + 1) + dst] + pos] = src;
}

// ---------------- PEARL PE + time PE + concat -> h0 [N,112] ----------------

__global__ __launch_bounds__(256) void pearl_h0_kernel(
    const float* __restrict__ x, const int* __restrict__ date,
    const int* __restrict__ off, const int* __restrict__ srcs,
    const float* __restrict__ pW, const float* __restrict__ pb,
    float* __restrict__ h0, int N, int E) {
    int lane = threadIdx.x & 63;
    int wid = blockIdx.x * 4 + (threadIdx.x >> 6);
    if (wid >= N) return;
    int n = __builtin_amdgcn_readfirstlane(wid);

    float acc = 0.f;
    int deg = 0;
    for (int r = 0; r < 5; r++) {
        int kb = off[(size_t)r * (N + 1) + n];
        int ke = off[(size_t)r * (N + 1) + n + 1];
        deg += ke - kb;
        const int* sp = srcs + (size_t)r * E;
        int k = kb;
        for (; k + 4 <= ke; k += 4) {
            int i0 = sp[k], i1 = sp[k + 1], i2 = sp[k + 2], i3 = sp[k + 3];
            float a0 = x[(size_t)i0 * 64 + lane];
            float a1 = x[(size_t)i1 * 64 + lane];
            float a2 = x[(size_t)i2 * 64 + lane];
            float a3 = x[(size_t)i3 * 64 + lane];
            acc += (a0 + a1) + (a2 + a3);
        }
        for (; k < ke; k++) acc += x[(size_t)sp[k] * 64 + lane];
    }
    float an = acc / fmaxf((float)deg, 1.0f);

    float s = (lane < 32) ? pb[lane] : 0.f;
#pragma unroll 8
    for (int c = 0; c < 64; c++) {
        float av = __shfl(an, c, 64);
        if (lane < 32) s = fmaf(av, pW[c * 32 + lane], s);
    }

    h0[(size_t)n * 112 + lane] = x[(size_t)n * 64 + lane];
    if (lane < 32) h0[(size_t)n * 112 + 64 + lane] = tanhf(s);
    if (lane < 16) {
        float t = (float)date[n] / 10000.0f;
        int i = lane & 7;
        float dv = expf((float)(2 * i) * (-0.57564627324851148f));
        float arg = t * dv;
        h0[(size_t)n * 112 + 96 + lane] = (lane < 8) ? sinf(arg) : cosf(arg);
    }
}

// ---------------- pack A [M,K] fp32 -> hi/lo bf16, MFMA-fragment-major ----------------

__global__ __launch_bounds__(256) void pack_a_kernel(
    const float* __restrict__ A, __bf16* __restrict__ Ah, __bf16* __restrict__ Al,
    int M, int K, int Mp, int KT) {
    int KG = KT * 4;
    int idx = blockIdx.x * 256 + threadIdx.x;
    if (idx >= Mp * KG) return;
    int m = idx / KG, kgg = idx - m * KG;
    int kt = kgg >> 2, kg = kgg & 3;
    int k0 = kt * 32 + kg * 8;
    int mt = m >> 4, mr = m & 15;
    size_t out = (((size_t)mt * KT + kt) * 64 + kg * 16 + mr) * 8;
    bf16x8 hv, lv;
#pragma unroll
    for (int j = 0; j < 8; j++) {
        int k = k0 + j;
        float v = (m < M && k < K) ? A[(size_t)m * K + k] : 0.f;
        __bf16 h = (__bf16)v;
        hv[j] = h;
        lv[j] = (__bf16)(v - (float)h);
    }
    *(bf16x8*)(Ah + out) = hv;
    *(bf16x8*)(Al + out) = lv;
}

// ---------------- pack all weights (21 tensors, grid.y selects) ----------------

__global__ __launch_bounds__(256) void pack_w_kernel(
    const float* __restrict__ Wl0, const float* __restrict__ Wr0,
    const float* __restrict__ Wl1, const float* __restrict__ Wr1,
    const float* __restrict__ W1,
    __bf16* __restrict__ Wph, __bf16* __restrict__ Wpl) {
    const int S0 = 32768, S1 = 65536;
    int t = blockIdx.y;
    const float* W;
    int K, Nc, KT;
    size_t dst;
    if (t < 5)       { W = Wl0 + (size_t)t * 112 * 256;        K = 112; Nc = 256; KT = 4; dst = (size_t)t * S0; }
    else if (t < 10) { W = Wr0 + (size_t)(t - 5) * 112 * 256;  K = 112; Nc = 256; KT = 4; dst = 163840 + (size_t)(t - 5) * S0; }
    else if (t < 15) { W = Wl1 + (size_t)(t - 10) * 256 * 256; K = 256; Nc = 256; KT = 8; dst = 327680 + (size_t)(t - 10) * S1; }
    else if (t < 20) { W = Wr1 + (size_t)(t - 15) * 256 * 256; K = 256; Nc = 256; KT = 8; dst = 655360 + (size_t)(t - 15) * S1; }
    else             { W = W1;                                  K = 256; Nc = 128; KT = 8; dst = 983040; }
    int entries = (Nc / 16) * KT * 64;
    int idx = blockIdx.x * 256 + threadIdx.x;
    if (idx >= entries) return;
    int nt = idx / (KT * 64);
    int rem = idx - nt * (KT * 64);
    int kt = rem >> 6, lane = rem & 63;
    int kg = lane >> 4, nr = lane & 15;
    bf16x8 hv, lv;
#pragma unroll
    for (int j = 0; j < 8; j++) {
        int k = kt * 32 + kg * 8 + j;
        float v = (k < K) ? W[(size_t)k * Nc + nt * 16 + nr] : 0.f;
        __bf16 h = (__bf16)v;
        hv[j] = h;
        lv[j] = (__bf16)(v - (float)h);
    }
    *(bf16x8*)(Wph + dst + (size_t)idx * 8) = hv;
    *(bf16x8*)(Wpl + dst + (size_t)idx * 8) = lv;
}

// ---------------- split-bf16 MFMA GEMM (3-pass) ----------------

__global__ __launch_bounds__(256) void gemm_mfma(
    const __bf16* __restrict__ Ah, const __bf16* __restrict__ Al,
    const __bf16* __restrict__ Bh0, const __bf16* __restrict__ Bl0, float* __restrict__ C0,
    const __bf16* __restrict__ Bh1, const __bf16* __restrict__ Bl1, float* __restrict__ C1,
    int M, int Nout, int KT,
    const float* __restrict__ bias, int do_relu) {
    const __bf16* Bh = blockIdx.z ? Bh1 : Bh0;
    const __bf16* Bl = blockIdx.z ? Bl1 : Bl0;
    float* C = blockIdx.z ? C1 : C0;

    __shared__ __bf16 sAh[8 * 512], sAl[8 * 512], sBh[8 * 512], sBl[8 * 512];

    int tid = threadIdx.x, lane = tid & 63, w = tid >> 6;
    int wr = w >> 1, wc = w & 1;
    int bx = blockIdx.x, by = blockIdx.y;

    f32x4 acc[4][4] = {};

    for (int kt = 0; kt < KT; ++kt) {
        int tl = w * 2;
        size_t a0 = ((size_t)(bx * 8 + tl) * KT + kt) * 512 + lane * 8;
        size_t a1 = ((size_t)(bx * 8 + tl + 1) * KT + kt) * 512 + lane * 8;
        size_t b0 = ((size_t)(by * 8 + tl) * KT + kt) * 512 + lane * 8;
        size_t b1 = ((size_t)(by * 8 + tl + 1) * KT + kt) * 512 + lane * 8;
        GLD16(Ah + a0, sAh + tl * 512);
        GLD16(Ah + a1, sAh + (tl + 1) * 512);
        GLD16(Al + a0, sAl + tl * 512);
        GLD16(Al + a1, sAl + (tl + 1) * 512);
        GLD16(Bh + b0, sBh + tl * 512);
        GLD16(Bh + b1, sBh + (tl + 1) * 512);
        GLD16(Bl + b0, sBl + tl * 512);
        GLD16(Bl + b1, sBl + (tl + 1) * 512);
        __syncthreads();

        bf16x8 ah[4], al[4], bh[4], bl[4];
#pragma unroll
        for (int i = 0; i < 4; i++) {
            ah[i] = *(const bf16x8*)(sAh + (wr * 4 + i) * 512 + lane * 8);
            al[i] = *(const bf16x8*)(sAl + (wr * 4 + i) * 512 + lane * 8);
            bh[i] = *(const bf16x8*)(sBh + (wc * 4 + i) * 512 + lane * 8);
            bl[i] = *(const bf16x8*)(sBl + (wc * 4 + i) * 512 + lane * 8);
        }
#pragma unroll
        for (int i = 0; i < 4; i++)
#pragma unroll
            for (int j = 0; j < 4; j++) {
                acc[i][j] = __builtin_amdgcn_mfma_f32_16x16x32_bf16(ah[i], bh[j], acc[i][j], 0, 0, 0);
                acc[i][j] = __builtin_amdgcn_mfma_f32_16x16x32_bf16(al[i], bh[j], acc[i][j], 0, 0, 0);
                acc[i][j] = __builtin_amdgcn_mfma_f32_16x16x32_bf16(ah[i], bl[j], acc[i][j], 0, 0, 0);
            }
        __syncthreads();
    }

    int rb = bx * 128 + wr * 64, cb = by * 128 + wc * 64;
#pragma unroll
    for (int i = 0; i < 4; i++) {
#pragma unroll
        for (int j = 0; j < 4; j++) {
            int row0 = rb + i * 16 + (lane >> 4) * 4;
            int col = cb + j * 16 + (lane & 15);
            float bv = bias ? bias[col] : 0.f;
#pragma unroll
            for (int r = 0; r < 4; r++) {
                int row = row0 + r;
                if (row < M) {
                    float v = acc[i][j][r] + bv;
                    if (do_relu) v = fmaxf(v, 0.f);
                    C[(size_t)row * Nout + col] = v;
                }
            }
        }
    }
}

// ---------------- fused GATv2: 4 edges/iter lane layout ----------------
// lane = e*16 + h*4 + q ; lane owns 16 channels (h*64+q*16..+15) of edge-slot e.
// Per iter: 4 edges, 2 shuffles (q-reduce), uniform-branch rescale (rare).
// End: online-softmax merge across the 4 e-groups, write 4 ch per lane.

__global__ __launch_bounds__(256) void gat_kernel(
    const float* __restrict__ xl, const float* __restrict__ xr,
    const float* __restrict__ att,
    const int* __restrict__ off, const int* __restrict__ srcs,
    float* __restrict__ conv, const float* __restrict__ binit,
    int N, int do_relu) {
    int lane = threadIdx.x & 63;
    int wid = blockIdx.x * 4 + (threadIdx.x >> 6);
    if (wid >= N) return;
    int n = __builtin_amdgcn_readfirstlane(wid);
    int e = lane >> 4;
    int sub = lane & 15;
    int cb = (sub >> 2) * 64 + (sub & 3) * 16;  // head*64 + q*16

    const float* xrp = xr + (size_t)n * 256 + cb;
    float4 r0 = *(const float4*)(xrp);
    float4 r1 = *(const float4*)(xrp + 4);
    float4 r2 = *(const float4*)(xrp + 8);
    float4 r3 = *(const float4*)(xrp + 12);
    float4 a0 = *(const float4*)(att + cb);
    float4 a1 = *(const float4*)(att + cb + 4);
    float4 a2 = *(const float4*)(att + cb + 8);
    float4 a3 = *(const float4*)(att + cb + 12);

    float m = -3.0e38f, d = 0.f;
    float4 A0 = {0.f, 0.f, 0.f, 0.f}, A1 = A0, A2 = A0, A3 = A0;

    int kb = off[n], ke = off[n + 1];
    if (kb < ke) {
        int kl = ke - 1;
        int ki = kb + e;
        int s = srcs[(ki <= kl) ? ki : kl];
        const float* xp = xl + (size_t)s * 256 + cb;
        float4 c0 = *(const float4*)(xp);
        float4 c1 = *(const float4*)(xp + 4);
        float4 c2 = *(const float4*)(xp + 8);
        float4 c3 = *(const float4*)(xp + 12);
        for (int k = kb; k < ke; k += 4) {
            int kn = k + 4 + e;
            int sn = srcs[(kn <= kl) ? kn : kl];
            const float* np = xl + (size_t)sn * 256 + cb;
            float4 n0 = *(const float4*)(np);
            float4 n1 = *(const float4*)(np + 4);
            float4 n2 = *(const float4*)(np + 8);
            float4 n3 = *(const float4*)(np + 12);

            float p = 0.f;
#define TERM(cc, rr, aa)                                                   \
    {                                                                      \
        float t;                                                           \
        t = cc.x + rr.x; t = (t > 0.f) ? t : 0.2f * t; p = fmaf(t, aa.x, p); \
        t = cc.y + rr.y; t = (t > 0.f) ? t : 0.2f * t; p = fmaf(t, aa.y, p); \
        t = cc.z + rr.z; t = (t > 0.f) ? t : 0.2f * t; p = fmaf(t, aa.z, p); \
        t = cc.w + rr.w; t = (t > 0.f) ? t : 0.2f * t; p = fmaf(t, aa.w, p); \
    }
            TERM(c0, r0, a0)
            TERM(c1, r1, a1)
            TERM(c2, r2, a2)
            TERM(c3, r3, a3)
#undef TERM
            p += __shfl_xor(p, 1, 64);
            p += __shfl_xor(p, 2, 64);
            bool valid = (k + e) < ke;
            if (!valid) p = -3.0e38f;

            if (__any(p > m)) {  // rare after warmup: ~ln(deg) times per node
                float nm = fmaxf(m, p);
                float sc = __expf(m - nm);
                d *= sc;
                A0.x *= sc; A0.y *= sc; A0.z *= sc; A0.w *= sc;
                A1.x *= sc; A1.y *= sc; A1.z *= sc; A1.w *= sc;
                A2.x *= sc; A2.y *= sc; A2.z *= sc; A2.w *= sc;
                A3.x *= sc; A3.y *= sc; A3.z *= sc; A3.w *= sc;
                m = nm;
            }
            float wg = valid ? __expf(p - m) : 0.f;
            d += wg;
            A0.x = fmaf(wg, c0.x, A0.x); A0.y = fmaf(wg, c0.y, A0.y);
            A0.z = fmaf(wg, c0.z, A0.z); A0.w = fmaf(wg, c0.w, A0.w);
            A1.x = fmaf(wg, c1.x, A1.x); A1.y = fmaf(wg, c1.y, A1.y);
            A1.z = fmaf(wg, c1.z, A1.z); A1.w = fmaf(wg, c1.w, A1.w);
            A2.x = fmaf(wg, c2.x, A2.x); A2.y = fmaf(wg, c2.y, A2.y);
            A2.z = fmaf(wg, c2.z, A2.z); A2.w = fmaf(wg, c2.w, A2.w);
            A3.x = fmaf(wg, c3.x, A3.x); A3.y = fmaf(wg, c3.y, A3.y);
            A3.z = fmaf(wg, c3.z, A3.z); A3.w = fmaf(wg, c3.w, A3.w);

            c0 = n0; c1 = n1; c2 = n2; c3 = n3;
        }
    }

    // merge online-softmax state across the 4 e-groups
    float M = fmaxf(m, __shfl_xor(m, 16, 64));
    M = fmaxf(M, __shfl_xor(M, 32, 64));
    float sc = __expf(m - M);
    d *= sc;
    d += __shfl_xor(d, 16, 64);
    d += __shfl_xor(d, 32, 64);
#define MRGC(comp)                              \
    comp *= sc;                                 \
    comp += __shfl_xor(comp, 16, 64);           \
    comp += __shfl_xor(comp, 32, 64);
    MRGC(A0.x) MRGC(A0.y) MRGC(A0.z) MRGC(A0.w)
    MRGC(A1.x) MRGC(A1.y) MRGC(A1.z) MRGC(A1.w)
    MRGC(A2.x) MRGC(A2.y) MRGC(A2.z) MRGC(A2.w)
    MRGC(A3.x) MRGC(A3.y) MRGC(A3.z) MRGC(A3.w)
#undef MRGC

    float inv = 1.0f / (d + 1e-16f);
    float4 R = (e == 0) ? A0 : (e == 1) ? A1 : (e == 2) ? A2 : A3;
    int wc = cb + e * 4;
    float* cp = conv + (size_t)n * 256 + wc;
    float4 cv;
    if (binit) {
        float4 s0 = *(const float4*)(binit + wc);
        float4 s1 = *(const float4*)(binit + 256 + wc);
        float4 s2 = *(const float4*)(binit + 512 + wc);
        float4 s3 = *(const float4*)(binit + 768 + wc);
        float4 s4 = *(const float4*)(binit + 1024 + wc);
        cv.x = s0.x + s1.x + s2.x + s3.x + s4.x;
        cv.y = s0.y + s1.y + s2.y + s3.y + s4.y;
        cv.z = s0.z + s1.z + s2.z + s3.z + s4.z;
        cv.w = s0.w + s1.w + s2.w + s3.w + s4.w;
    } else {
        cv = *(float4*)cp;
    }
    cv.x = fmaf(R.x, inv, cv.x);
    cv.y = fmaf(R.y, inv, cv.y);
    cv.z = fmaf(R.z, inv, cv.z);
    cv.w = fmaf(R.w, inv, cv.w);
    if (do_relu) {
        cv.x = fmaxf(cv.x, 0.f);
        cv.y = fmaxf(cv.y, 0.f);
        cv.z = fmaxf(cv.z, 0.f);
        cv.w = fmaxf(cv.w, 0.f);
    }
    *(float4*)cp = cv;
}

// ---------------- head ----------------

__global__ __launch_bounds__(256) void head_kernel(const float* __restrict__ hm,
                                                   const float* __restrict__ W2,
                                                   const float* __restrict__ b2,
                                                   float* __restrict__ out, int N) {
    int lane = threadIdx.x & 63;
    int wid = blockIdx.x * 4 + (threadIdx.x >> 6);
    if (wid >= N) return;
    int n = __builtin_amdgcn_readfirstlane(wid);
    float a0 = hm[(size_t)n * 128 + lane];
    float a1 = hm[(size_t)n * 128 + 64 + lane];
    float s0 = a0 * W2[lane * 3 + 0] + a1 * W2[(64 + lane) * 3 + 0];
    float s1 = a0 * W2[lane * 3 + 1] + a1 * W2[(64 + lane) * 3 + 1];
    float s2 = a0 * W2[lane * 3 + 2] + a1 * W2[(64 + lane) * 3 + 2];
#pragma unroll
    for (int sft = 1; sft < 64; sft <<= 1) {
        s0 += __shfl_xor(s0, sft, 64);
        s1 += __shfl_xor(s1, sft, 64);
        s2 += __shfl_xor(s2, sft, 64);
    }
    if (lane == 0) {
        out[(size_t)n * 3 + 0] = s0 + b2[0];
        out[(size_t)n * 3 + 1] = s1 + b2[1];
        out[(size_t)n * 3 + 2] = s2 + b2[2];
    }
}

// ---------------- launch ----------------

extern "C" void kernel_launch(void* const* d_in, const int* in_sizes, int n_in,
                              void* d_out, int out_size, void* d_ws, size_t ws_size,
                              hipStream_t stream) {
    const float* x    = (const float*)d_in[0];
    const int* date   = (const int*)d_in[1];
    const int* ei     = (const int*)d_in[2];
    const float* pW   = (const float*)d_in[3];
    const float* pb   = (const float*)d_in[4];
    const float* Wl0  = (const float*)d_in[5];
    const float* Wr0  = (const float*)d_in[6];
    const float* att0 = (const float*)d_in[7];
    const float* b0   = (const float*)d_in[8];
    const float* Wl1  = (const float*)d_in[9];
    const float* Wr1  = (const float*)d_in[10];
    const float* att1 = (const float*)d_in[11];
    const float* b1   = (const float*)d_in[12];
    // d_in[13..15] = aggW/aggb/agga — rel_agg is identity (h_rel broadcast), skipped
    const float* outW1 = (const float*)d_in[16];
    const float* outb1 = (const float*)d_in[17];
    const float* outW2 = (const float*)d_in[18];
    const float* outb2 = (const float*)d_in[19];
    float* out = (float*)d_out;

    int N = in_sizes[0] / 64;
    int E = in_sizes[2] / 10;
    int Mp = ((N + 127) / 128) * 128;
    int MT = Mp / 128;
    int NC = (N + 1023) / 1024;  // scan chunks per relation

    char* ws = (char*)d_ws;
    size_t o = 0;
    auto alloc = [&](size_t bytes) -> char* {
        char* p = ws + o;
        o += (bytes + 255) & ~(size_t)255;
        return p;
    };
    int* cur      = (int*)alloc((size_t)5 * N * 4);
    int* csrOff   = (int*)alloc((size_t)5 * (N + 1) * 4);
    int* csrSrc   = (int*)alloc((size_t)5 * E * 4);
    int* csums    = (int*)alloc((size_t)5 * NC * 4);
    float* h0     = (float*)alloc((size_t)N * 112 * 4);
    float* bufA   = (float*)alloc((size_t)N * 256 * 4);
    float* bufB   = (float*)alloc((size_t)N * 256 * 4);
    float* xl     = (float*)alloc((size_t)N * 256 * 4);
    float* xr     = (float*)alloc((size_t)N * 256 * 4);
    __bf16* Aph   = (__bf16*)alloc((size_t)Mp * 256 * 2);
    __bf16* Apl   = (__bf16*)alloc((size_t)Mp * 256 * 2);
    __bf16* Wph   = (__bf16*)alloc((size_t)1015808 * 2);
    __bf16* Wpl   = (__bf16*)alloc((size_t)1015808 * 2);
    float* hmid   = xl;  // head GEMM output reuses xl (free after layer-1 GAT)
    (void)ws_size;

    const size_t S0 = 32768, S1 = 65536;
    const size_t oWl0 = 0, oWr0 = 163840, oWl1 = 327680, oWr1 = 655360, oW1 = 983040;

    int totE = 5 * E;

    // CSR by dst, per relation
    hipMemsetAsync(cur, 0, (size_t)5 * N * 4, stream);
    count_kernel<<<(totE + 255) / 256, 256, 0, stream>>>(ei, cur, N, E);
    scanA_kernel<<<dim3(NC, 5), 256, 0, stream>>>(cur, csrOff, csums, N, NC);
    scanB_kernel<<<1, 64, 0, stream>>>(csums, csrOff, N, NC);
    scanC_kernel<<<dim3(NC, 5), 256, 0, stream>>>(csrOff, csums, N, NC);
    hipMemsetAsync(cur, 0, (size_t)5 * N * 4, stream);
    scatter_kernel<<<(totE + 255) / 256, 256, 0, stream>>>(ei, csrOff, cur, csrSrc, N, E);

    // pearl PE + time PE + concat
    pearl_h0_kernel<<<(N + 3) / 4, 256, 0, stream>>>(x, date, csrOff, csrSrc, pW, pb, h0, N, E);

    // pack all weights (hi/lo split)
    pack_w_kernel<<<dim3(32, 21, 1), 256, 0, stream>>>(Wl0, Wr0, Wl1, Wr1, outW1, Wph, Wpl);

    dim3 gemmGrid(MT, 2, 2);

    // ----- layer 0 (K=112 -> Kp=128, KT=4) -----
    pack_a_kernel<<<(Mp * 16 + 255) / 256, 256, 0, stream>>>(h0, Aph, Apl, N, 112, Mp, 4);
    for (int r = 0; r < 5; r++) {
        gemm_mfma<<<gemmGrid, 256, 0, stream>>>(
            Aph, Apl,
            Wph + oWl0 + r * S0, Wpl + oWl0 + r * S0, xl,
            Wph + oWr0 + r * S0, Wpl + oWr0 + r * S0, xr,
            N, 256, 4, nullptr, 0);
        gat_kernel<<<(N + 3) / 4, 256, 0, stream>>>(xl, xr, att0 + (size_t)r * 256,
                                                    csrOff + (size_t)r * (N + 1),
                                                    csrSrc + (size_t)r * E, bufA,
                                                    (r == 0) ? b0 : nullptr, N, r == 4);
    }

    // ----- layer 1 (K=256, KT=8) -----
    pack_a_kernel<<<(Mp * 32 + 255) / 256, 256, 0, stream>>>(bufA, Aph, Apl, N, 256, Mp, 8);
    for (int r = 0; r < 5; r++) {
        gemm_mfma<<<gemmGrid, 256, 0, stream>>>(
            Aph, Apl,
            Wph + oWl1 + r * S1, Wpl + oWl1 + r * S1, xl,
            Wph + oWr1 + r * S1, Wpl + oWr1 + r * S1, xr,
            N, 256, 8, nullptr, 0);
        gat_kernel<<<(N + 3) / 4, 256, 0, stream>>>(xl, xr, att1 + (size_t)r * 256,
                                                    csrOff + (size_t)r * (N + 1),
                                                    csrSrc + (size_t)r * E, bufB,
                                                    (r == 0) ? b1 : nullptr, N, r == 4);
    }

    // ----- MLP head: hmid = relu(bufB @ outW1 + outb1) -----
    pack_a_kernel<<<(Mp * 32 + 255) / 256, 256, 0, stream>>>(bufB, Aph, Apl, N, 256, Mp, 8);
    dim3 headGrid(MT, 1, 1);
    gemm_mfma<<<headGrid, 256, 0, stream>>>(
        Aph, Apl,
        Wph + oW1, Wpl + oW1, hmid,
        Wph + oW1, Wpl + oW1, hmid,
        N, 128, 8, outb1, 1);
    head_kernel<<<(N + 3) / 4, 256, 0, stream>>>(hmid, outW2, outb2, out, N);
}

// Round 5
// 994.893 us; speedup vs baseline: 2.1841x; 1.1818x over previous
//
#include <hip/hip_runtime.h>
#include <math.h>

typedef __bf16 bf16x8 __attribute__((ext_vector_type(8)));
typedef float f32x4 __attribute__((ext_vector_type(4)));
typedef unsigned short u16x8 __attribute__((ext_vector_type(8)));

#define GLD16(src, dst)                                                        \
    __builtin_amdgcn_global_load_lds(                                          \
        (const __attribute__((address_space(1))) void*)(src),                  \
        (__attribute__((address_space(3))) void*)(dst), 16, 0, 0)

__device__ inline float bf2f(unsigned short u) {
    union { unsigned int i; float f; } c;
    c.i = ((unsigned int)u) << 16;
    return c.f;
}

// ---------------- CSR build ----------------

__global__ __launch_bounds__(256) void count_kernel(const int* __restrict__ ei,
                                                    int* __restrict__ cnt, int N, int E) {
    int idx = blockIdx.x * 256 + threadIdx.x;
    if (idx >= 5 * E) return;
    int r = idx / E;
    int e = idx - r * E;
    int dst = ei[(size_t)r * 2 * E + E + e];
    atomicAdd(&cnt[r * N + dst], 1);
}

__global__ __launch_bounds__(256) void scanA_kernel(const int* __restrict__ cnt,
                                                    int* __restrict__ off,
                                                    int* __restrict__ csums, int N, int NC) {
    int r = blockIdx.y, c = blockIdx.x, t = threadIdx.x;
    int idx0 = c * 1024 + t * 4;
    int v0 = (idx0 + 0 < N) ? cnt[r * N + idx0 + 0] : 0;
    int v1 = (idx0 + 1 < N) ? cnt[r * N + idx0 + 1] : 0;
    int v2 = (idx0 + 2 < N) ? cnt[r * N + idx0 + 2] : 0;
    int v3 = (idx0 + 3 < N) ? cnt[r * N + idx0 + 3] : 0;
    int ts = v0 + v1 + v2 + v3;
    __shared__ int sd[256];
    sd[t] = ts;
    __syncthreads();
    for (int s = 1; s < 256; s <<= 1) {
        int add = (t >= s) ? sd[t - s] : 0;
        __syncthreads();
        sd[t] += add;
        __syncthreads();
    }
    int excl = sd[t] - ts;
    size_t base = (size_t)r * (N + 1);
    if (idx0 + 0 < N) off[base + idx0 + 0] = excl;
    if (idx0 + 1 < N) off[base + idx0 + 1] = excl + v0;
    if (idx0 + 2 < N) off[base + idx0 + 2] = excl + v0 + v1;
    if (idx0 + 3 < N) off[base + idx0 + 3] = excl + v0 + v1 + v2;
    if (t == 255) csums[r * NC + c] = sd[255];
}

__global__ __launch_bounds__(64) void scanB_kernel(int* __restrict__ csums,
                                                   int* __restrict__ off, int N, int NC) {
    int r = threadIdx.x;
    if (r < 5) {
        int run = 0;
        for (int c = 0; c < NC; c++) {
            int t = csums[r * NC + c];
            csums[r * NC + c] = run;
            run += t;
        }
        off[(size_t)r * (N + 1) + N] = run;
    }
}

__global__ __launch_bounds__(256) void scanC_kernel(int* __restrict__ off,
                                                    const int* __restrict__ csums,
                                                    int N, int NC) {
    int r = blockIdx.y, c = blockIdx.x, t = threadIdx.x;
    int add = csums[r * NC + c];
    int idx0 = c * 1024 + t * 4;
    size_t base = (size_t)r * (N + 1);
#pragma unroll
    for (int j = 0; j < 4; j++)
        if (idx0 + j < N) off[base + idx0 + j] += add;
}

__global__ __launch_bounds__(256) void scatter_kernel(const int* __restrict__ ei,
                                                      const int* __restrict__ off,
                                                      int* __restrict__ cur,
                                                      int* __restrict__ srcs, int N, int E) {
    int idx = blockIdx.x * 256 + threadIdx.x;
    if (idx >= 5 * E) return;
    int r = idx / E;
    int e = idx - r * E;
    int src = ei[(size_t)r * 2 * E + e];
    int dst = ei[(size_t)r * 2 * E + E + e];
    int pos = atomicAdd(&cur[r * N + dst], 1);
    srcs[(size_t)r * E + off[(size_t)r * (N + 1) + dst] + pos] = src;
}

// ---------------- PEARL PE + time PE + concat -> h0 [N,112] ----------------

__global__ __launch_bounds__(256) void pearl_h0_kernel(
    const float* __restrict__ x, const int* __restrict__ date,
    const int* __restrict__ off, const int* __restrict__ srcs,
    const float* __restrict__ pW, const float* __restrict__ pb,
    float* __restrict__ h0, int N, int E) {
    int lane = threadIdx.x & 63;
    int wid = blockIdx.x * 4 + (threadIdx.x >> 6);
    if (wid >= N) return;
    int n = __builtin_amdgcn_readfirstlane(wid);

    float acc = 0.f;
    int deg = 0;
    // unroll-by-8 gather: 8 independent row loads in flight
    for (int r = 0; r < 5; r++) {
        int kb = off[(size_t)r * (N + 1) + n];
        int ke = off[(size_t)r * (N + 1) + n + 1];
        deg += ke - kb;
        const int* sp = srcs + (size_t)r * E;
        int k = kb;
        for (; k + 8 <= ke; k += 8) {
            int i0 = sp[k], i1 = sp[k + 1], i2 = sp[k + 2], i3 = sp[k + 3];
            int i4 = sp[k + 4], i5 = sp[k + 5], i6 = sp[k + 6], i7 = sp[k + 7];
            float a0 = x[(size_t)i0 * 64 + lane];
            float a1 = x[(size_t)i1 * 64 + lane];
            float a2 = x[(size_t)i2 * 64 + lane];
            float a3 = x[(size_t)i3 * 64 + lane];
            float a4 = x[(size_t)i4 * 64 + lane];
            float a5 = x[(size_t)i5 * 64 + lane];
            float a6 = x[(size_t)i6 * 64 + lane];
            float a7 = x[(size_t)i7 * 64 + lane];
            acc += ((a0 + a1) + (a2 + a3)) + ((a4 + a5) + (a6 + a7));
        }
        for (; k + 4 <= ke; k += 4) {
            int i0 = sp[k], i1 = sp[k + 1], i2 = sp[k + 2], i3 = sp[k + 3];
            float a0 = x[(size_t)i0 * 64 + lane];
            float a1 = x[(size_t)i1 * 64 + lane];
            float a2 = x[(size_t)i2 * 64 + lane];
            float a3 = x[(size_t)i3 * 64 + lane];
            acc += (a0 + a1) + (a2 + a3);
        }
        for (; k < ke; k++) acc += x[(size_t)sp[k] * 64 + lane];
    }
    float an = acc / fmaxf((float)deg, 1.0f);

    float s = (lane < 32) ? pb[lane] : 0.f;
#pragma unroll 8
    for (int c = 0; c < 64; c++) {
        float av = __shfl(an, c, 64);
        if (lane < 32) s = fmaf(av, pW[c * 32 + lane], s);
    }

    h0[(size_t)n * 112 + lane] = x[(size_t)n * 64 + lane];
    if (lane < 32) h0[(size_t)n * 112 + 64 + lane] = tanhf(s);
    if (lane < 16) {
        float t = (float)date[n] / 10000.0f;
        int i = lane & 7;
        float dv = expf((float)(2 * i) * (-0.57564627324851148f));
        float arg = t * dv;
        h0[(size_t)n * 112 + 96 + lane] = (lane < 8) ? sinf(arg) : cosf(arg);
    }
}

// ---------------- pack A [M,K] fp32 -> hi/lo bf16, MFMA-fragment-major ----------------

__global__ __launch_bounds__(256) void pack_a_kernel(
    const float* __restrict__ A, __bf16* __restrict__ Ah, __bf16* __restrict__ Al,
    int M, int K, int Mp, int KT) {
    int KG = KT * 4;
    int idx = blockIdx.x * 256 + threadIdx.x;
    if (idx >= Mp * KG) return;
    int m = idx / KG, kgg = idx - m * KG;
    int kt = kgg >> 2, kg = kgg & 3;
    int k0 = kt * 32 + kg * 8;
    int mt = m >> 4, mr = m & 15;
    size_t out = (((size_t)mt * KT + kt) * 64 + kg * 16 + mr) * 8;
    bf16x8 hv, lv;
#pragma unroll
    for (int j = 0; j < 8; j++) {
        int k = k0 + j;
        float v = (m < M && k < K) ? A[(size_t)m * K + k] : 0.f;
        __bf16 h = (__bf16)v;
        hv[j] = h;
        lv[j] = (__bf16)(v - (float)h);
    }
    *(bf16x8*)(Ah + out) = hv;
    *(bf16x8*)(Al + out) = lv;
}

// ---------------- pack all weights (21 tensors, grid.y selects) ----------------

__global__ __launch_bounds__(256) void pack_w_kernel(
    const float* __restrict__ Wl0, const float* __restrict__ Wr0,
    const float* __restrict__ Wl1, const float* __restrict__ Wr1,
    const float* __restrict__ W1,
    __bf16* __restrict__ Wph, __bf16* __restrict__ Wpl) {
    const int S0 = 32768, S1 = 65536;
    int t = blockIdx.y;
    const float* W;
    int K, Nc, KT;
    size_t dst;
    if (t < 5)       { W = Wl0 + (size_t)t * 112 * 256;        K = 112; Nc = 256; KT = 4; dst = (size_t)t * S0; }
    else if (t < 10) { W = Wr0 + (size_t)(t - 5) * 112 * 256;  K = 112; Nc = 256; KT = 4; dst = 163840 + (size_t)(t - 5) * S0; }
    else if (t < 15) { W = Wl1 + (size_t)(t - 10) * 256 * 256; K = 256; Nc = 256; KT = 8; dst = 327680 + (size_t)(t - 10) * S1; }
    else if (t < 20) { W = Wr1 + (size_t)(t - 15) * 256 * 256; K = 256; Nc = 256; KT = 8; dst = 655360 + (size_t)(t - 15) * S1; }
    else             { W = W1;                                  K = 256; Nc = 128; KT = 8; dst = 983040; }
    int entries = (Nc / 16) * KT * 64;
    int idx = blockIdx.x * 256 + threadIdx.x;
    if (idx >= entries) return;
    int nt = idx / (KT * 64);
    int rem = idx - nt * (KT * 64);
    int kt = rem >> 6, lane = rem & 63;
    int kg = lane >> 4, nr = lane & 15;
    bf16x8 hv, lv;
#pragma unroll
    for (int j = 0; j < 8; j++) {
        int k = kt * 32 + kg * 8 + j;
        float v = (k < K) ? W[(size_t)k * Nc + nt * 16 + nr] : 0.f;
        __bf16 h = (__bf16)v;
        hv[j] = h;
        lv[j] = (__bf16)(v - (float)h);
    }
    *(bf16x8*)(Wph + dst + (size_t)idx * 8) = hv;
    *(bf16x8*)(Wpl + dst + (size_t)idx * 8) = lv;
}

// ---------------- split-bf16 MFMA GEMM ----------------
// np (per z-slice): 3 = AhBh+AlBh+AhBl (near-fp32), 1 = AhBh only (logit-grade).
// out_bf16: write C as bf16 (for GAT consumption) or f32.

__global__ __launch_bounds__(256) void gemm_mfma(
    const __bf16* __restrict__ Ah, const __bf16* __restrict__ Al,
    const __bf16* __restrict__ Bh0, const __bf16* __restrict__ Bl0, void* __restrict__ C0,
    const __bf16* __restrict__ Bh1, const __bf16* __restrict__ Bl1, void* __restrict__ C1,
    int M, int Nout, int KT,
    const float* __restrict__ bias, int do_relu, int np0, int np1, int out_bf16) {
    const __bf16* Bh = blockIdx.z ? Bh1 : Bh0;
    const __bf16* Bl = blockIdx.z ? Bl1 : Bl0;
    void* C = blockIdx.z ? C1 : C0;
    int np = blockIdx.z ? np1 : np0;

    __shared__ __bf16 sAh[8 * 512], sAl[8 * 512], sBh[8 * 512], sBl[8 * 512];

    int tid = threadIdx.x, lane = tid & 63, w = tid >> 6;
    int wr = w >> 1, wc = w & 1;
    int bx = blockIdx.x, by = blockIdx.y;

    f32x4 acc[4][4] = {};

    for (int kt = 0; kt < KT; ++kt) {
        int tl = w * 2;
        size_t a0 = ((size_t)(bx * 8 + tl) * KT + kt) * 512 + lane * 8;
        size_t a1 = ((size_t)(bx * 8 + tl + 1) * KT + kt) * 512 + lane * 8;
        size_t b0 = ((size_t)(by * 8 + tl) * KT + kt) * 512 + lane * 8;
        size_t b1 = ((size_t)(by * 8 + tl + 1) * KT + kt) * 512 + lane * 8;
        GLD16(Ah + a0, sAh + tl * 512);
        GLD16(Ah + a1, sAh + (tl + 1) * 512);
        GLD16(Bh + b0, sBh + tl * 512);
        GLD16(Bh + b1, sBh + (tl + 1) * 512);
        if (np == 3) {
            GLD16(Al + a0, sAl + tl * 512);
            GLD16(Al + a1, sAl + (tl + 1) * 512);
            GLD16(Bl + b0, sBl + tl * 512);
            GLD16(Bl + b1, sBl + (tl + 1) * 512);
        }
        __syncthreads();

        bf16x8 ah[4], al[4], bh[4], bl[4];
#pragma unroll
        for (int i = 0; i < 4; i++) {
            ah[i] = *(const bf16x8*)(sAh + (wr * 4 + i) * 512 + lane * 8);
            bh[i] = *(const bf16x8*)(sBh + (wc * 4 + i) * 512 + lane * 8);
        }
        if (np == 3) {
#pragma unroll
            for (int i = 0; i < 4; i++) {
                al[i] = *(const bf16x8*)(sAl + (wr * 4 + i) * 512 + lane * 8);
                bl[i] = *(const bf16x8*)(sBl + (wc * 4 + i) * 512 + lane * 8);
            }
        }
#pragma unroll
        for (int i = 0; i < 4; i++)
#pragma unroll
            for (int j = 0; j < 4; j++) {
                acc[i][j] = __builtin_amdgcn_mfma_f32_16x16x32_bf16(ah[i], bh[j], acc[i][j], 0, 0, 0);
                if (np == 3) {
                    acc[i][j] = __builtin_amdgcn_mfma_f32_16x16x32_bf16(al[i], bh[j], acc[i][j], 0, 0, 0);
                    acc[i][j] = __builtin_amdgcn_mfma_f32_16x16x32_bf16(ah[i], bl[j], acc[i][j], 0, 0, 0);
                }
            }
        __syncthreads();
    }

    int rb = bx * 128 + wr * 64, cb = by * 128 + wc * 64;
#pragma unroll
    for (int i = 0; i < 4; i++) {
#pragma unroll
        for (int j = 0; j < 4; j++) {
            int row0 = rb + i * 16 + (lane >> 4) * 4;
            int col = cb + j * 16 + (lane & 15);
            float bv = bias ? bias[col] : 0.f;
#pragma unroll
            for (int r = 0; r < 4; r++) {
                int row = row0 + r;
                if (row < M) {
                    float v = acc[i][j][r] + bv;
                    if (do_relu) v = fmaxf(v, 0.f);
                    if (out_bf16)
                        ((__bf16*)C)[(size_t)row * Nout + col] = (__bf16)v;
                    else
                        ((float*)C)[(size_t)row * Nout + col] = v;
                }
            }
        }
    }
}

// ---------------- fused GATv2: 4 edges/iter, bf16 xl/xr gather ----------------
// lane = e*16 + h*4 + q ; lane owns 16 channels (h*64+q*16..+15) of edge-slot e.

__global__ __launch_bounds__(256) void gat_kernel(
    const unsigned short* __restrict__ xl, const unsigned short* __restrict__ xr,
    const float* __restrict__ att,
    const int* __restrict__ off, const int* __restrict__ srcs,
    float* __restrict__ conv, const float* __restrict__ binit,
    int N, int do_relu) {
    int lane = threadIdx.x & 63;
    int wid = blockIdx.x * 4 + (threadIdx.x >> 6);
    if (wid >= N) return;
    int n = __builtin_amdgcn_readfirstlane(wid);
    int e = lane >> 4;
    int sub = lane & 15;
    int cb = (sub >> 2) * 64 + (sub & 3) * 16;  // head*64 + q*16

    float rv[16], av[16];
    {
        const unsigned short* xrp = xr + (size_t)n * 256 + cb;
        u16x8 q0 = *(const u16x8*)(xrp);
        u16x8 q1 = *(const u16x8*)(xrp + 8);
#pragma unroll
        for (int j = 0; j < 8; j++) { rv[j] = bf2f(q0[j]); rv[8 + j] = bf2f(q1[j]); }
#pragma unroll
        for (int j = 0; j < 16; j += 4) {
            float4 a = *(const float4*)(att + cb + j);
            av[j] = a.x; av[j + 1] = a.y; av[j + 2] = a.z; av[j + 3] = a.w;
        }
    }

    float m = -3.0e38f, d = 0.f;
    float A[16];
#pragma unroll
    for (int j = 0; j < 16; j++) A[j] = 0.f;

    int kb = off[n], ke = off[n + 1];
    if (kb < ke) {
        int kl = ke - 1;
        int ki = kb + e;
        int s = srcs[(ki <= kl) ? ki : kl];
        float c[16];
        {
            const unsigned short* xp = xl + (size_t)s * 256 + cb;
            u16x8 q0 = *(const u16x8*)(xp);
            u16x8 q1 = *(const u16x8*)(xp + 8);
#pragma unroll
            for (int j = 0; j < 8; j++) { c[j] = bf2f(q0[j]); c[8 + j] = bf2f(q1[j]); }
        }
        for (int k = kb; k < ke; k += 4) {
            int kn = k + 4 + e;
            int sn = srcs[(kn <= kl) ? kn : kl];
            const unsigned short* np_ = xl + (size_t)sn * 256 + cb;
            u16x8 n0 = *(const u16x8*)(np_);
            u16x8 n1 = *(const u16x8*)(np_ + 8);

            float p = 0.f;
#pragma unroll
            for (int j = 0; j < 16; j++) {
                float t = c[j] + rv[j];
                t = (t > 0.f) ? t : 0.2f * t;
                p = fmaf(t, av[j], p);
            }
            p += __shfl_xor(p, 1, 64);
            p += __shfl_xor(p, 2, 64);
            bool valid = (k + e) < ke;
            if (!valid) p = -3.0e38f;

            if (__any(p > m)) {  // rare: ~ln(deg) times per node
                float nm = fmaxf(m, p);
                float sc = __expf(m - nm);
                d *= sc;
#pragma unroll
                for (int j = 0; j < 16; j++) A[j] *= sc;
                m = nm;
            }
            float wg = valid ? __expf(p - m) : 0.f;
            d += wg;
#pragma unroll
            for (int j = 0; j < 16; j++) A[j] = fmaf(wg, c[j], A[j]);

#pragma unroll
            for (int j = 0; j < 8; j++) { c[j] = bf2f(n0[j]); c[8 + j] = bf2f(n1[j]); }
        }
    }

    // merge online-softmax state across the 4 e-groups
    float M = fmaxf(m, __shfl_xor(m, 16, 64));
    M = fmaxf(M, __shfl_xor(M, 32, 64));
    float sc = __expf(m - M);
    d *= sc;
    d += __shfl_xor(d, 16, 64);
    d += __shfl_xor(d, 32, 64);
#pragma unroll
    for (int j = 0; j < 16; j++) {
        A[j] *= sc;
        A[j] += __shfl_xor(A[j], 16, 64);
        A[j] += __shfl_xor(A[j], 32, 64);
    }

    float inv = 1.0f / (d + 1e-16f);
    int wc = cb + e * 4;
    float R[4] = {A[e * 4], A[e * 4 + 1], A[e * 4 + 2], A[e * 4 + 3]};
    float* cp = conv + (size_t)n * 256 + wc;
    float4 cv;
    if (binit) {
        float4 s0 = *(const float4*)(binit + wc);
        float4 s1 = *(const float4*)(binit + 256 + wc);
        float4 s2 = *(const float4*)(binit + 512 + wc);
        float4 s3 = *(const float4*)(binit + 768 + wc);
        float4 s4 = *(const float4*)(binit + 1024 + wc);
        cv.x = s0.x + s1.x + s2.x + s3.x + s4.x;
        cv.y = s0.y + s1.y + s2.y + s3.y + s4.y;
        cv.z = s0.z + s1.z + s2.z + s3.z + s4.z;
        cv.w = s0.w + s1.w + s2.w + s3.w + s4.w;
    } else {
        cv = *(float4*)cp;
    }
    cv.x = fmaf(R[0], inv, cv.x);
    cv.y = fmaf(R[1], inv, cv.y);
    cv.z = fmaf(R[2], inv, cv.z);
    cv.w = fmaf(R[3], inv, cv.w);
    if (do_relu) {
        cv.x = fmaxf(cv.x, 0.f);
        cv.y = fmaxf(cv.y, 0.f);
        cv.z = fmaxf(cv.z, 0.f);
        cv.w = fmaxf(cv.w, 0.f);
    }
    *(float4*)cp = cv;
}

// ---------------- head ----------------

__global__ __launch_bounds__(256) void head_kernel(const float* __restrict__ hm,
                                                   const float* __restrict__ W2,
                                                   const float* __restrict__ b2,
                                                   float* __restrict__ out, int N) {
    int lane = threadIdx.x & 63;
    int wid = blockIdx.x * 4 + (threadIdx.x >> 6);
    if (wid >= N) return;
    int n = __builtin_amdgcn_readfirstlane(wid);
    float a0 = hm[(size_t)n * 128 + lane];
    float a1 = hm[(size_t)n * 128 + 64 + lane];
    float s0 = a0 * W2[lane * 3 + 0] + a1 * W2[(64 + lane) * 3 + 0];
    float s1 = a0 * W2[lane * 3 + 1] + a1 * W2[(64 + lane) * 3 + 1];
    float s2 = a0 * W2[lane * 3 + 2] + a1 * W2[(64 + lane) * 3 + 2];
#pragma unroll
    for (int sft = 1; sft < 64; sft <<= 1) {
        s0 += __shfl_xor(s0, sft, 64);
        s1 += __shfl_xor(s1, sft, 64);
        s2 += __shfl_xor(s2, sft, 64);
    }
    if (lane == 0) {
        out[(size_t)n * 3 + 0] = s0 + b2[0];
        out[(size_t)n * 3 + 1] = s1 + b2[1];
        out[(size_t)n * 3 + 2] = s2 + b2[2];
    }
}

// ---------------- launch ----------------

extern "C" void kernel_launch(void* const* d_in, const int* in_sizes, int n_in,
                              void* d_out, int out_size, void* d_ws, size_t ws_size,
                              hipStream_t stream) {
    const float* x    = (const float*)d_in[0];
    const int* date   = (const int*)d_in[1];
    const int* ei     = (const int*)d_in[2];
    const float* pW   = (const float*)d_in[3];
    const float* pb   = (const float*)d_in[4];
    const float* Wl0  = (const float*)d_in[5];
    const float* Wr0  = (const float*)d_in[6];
    const float* att0 = (const float*)d_in[7];
    const float* b0   = (const float*)d_in[8];
    const float* Wl1  = (const float*)d_in[9];
    const float* Wr1  = (const float*)d_in[10];
    const float* att1 = (const float*)d_in[11];
    const float* b1   = (const float*)d_in[12];
    // d_in[13..15] = aggW/aggb/agga — rel_agg is identity (h_rel broadcast), skipped
    const float* outW1 = (const float*)d_in[16];
    const float* outb1 = (const float*)d_in[17];
    const float* outW2 = (const float*)d_in[18];
    const float* outb2 = (const float*)d_in[19];
    float* out = (float*)d_out;

    int N = in_sizes[0] / 64;
    int E = in_sizes[2] / 10;
    int Mp = ((N + 127) / 128) * 128;
    int MT = Mp / 128;
    int NC = (N + 1023) / 1024;

    char* ws = (char*)d_ws;
    size_t o = 0;
    auto alloc = [&](size_t bytes) -> char* {
        char* p = ws + o;
        o += (bytes + 255) & ~(size_t)255;
        return p;
    };
    int* cur      = (int*)alloc((size_t)5 * N * 4);
    int* csrOff   = (int*)alloc((size_t)5 * (N + 1) * 4);
    int* csrSrc   = (int*)alloc((size_t)5 * E * 4);
    int* csums    = (int*)alloc((size_t)5 * NC * 4);
    float* h0     = (float*)alloc((size_t)N * 112 * 4);
    float* bufA   = (float*)alloc((size_t)N * 256 * 4);
    float* bufB   = (float*)alloc((size_t)N * 256 * 4);
    unsigned short* xl = (unsigned short*)alloc((size_t)N * 256 * 2);
    unsigned short* xr = (unsigned short*)alloc((size_t)N * 256 * 2);
    __bf16* Aph   = (__bf16*)alloc((size_t)Mp * 256 * 2);
    __bf16* Apl   = (__bf16*)alloc((size_t)Mp * 256 * 2);
    __bf16* Wph   = (__bf16*)alloc((size_t)1015808 * 2);
    __bf16* Wpl   = (__bf16*)alloc((size_t)1015808 * 2);
    float* hmid   = (float*)xl;  // N*128*4 == N*256*2 bytes, free after layer-1 GAT
    (void)ws_size;

    const size_t S0 = 32768, S1 = 65536;
    const size_t oWl0 = 0, oWr0 = 163840, oWl1 = 327680, oWr1 = 655360, oW1 = 983040;

    int totE = 5 * E;

    // CSR by dst, per relation
    hipMemsetAsync(cur, 0, (size_t)5 * N * 4, stream);
    count_kernel<<<(totE + 255) / 256, 256, 0, stream>>>(ei, cur, N, E);
    scanA_kernel<<<dim3(NC, 5), 256, 0, stream>>>(cur, csrOff, csums, N, NC);
    scanB_kernel<<<1, 64, 0, stream>>>(csums, csrOff, N, NC);
    scanC_kernel<<<dim3(NC, 5), 256, 0, stream>>>(csrOff, csums, N, NC);
    hipMemsetAsync(cur, 0, (size_t)5 * N * 4, stream);
    scatter_kernel<<<(totE + 255) / 256, 256, 0, stream>>>(ei, csrOff, cur, csrSrc, N, E);

    // pearl PE + time PE + concat
    pearl_h0_kernel<<<(N + 3) / 4, 256, 0, stream>>>(x, date, csrOff, csrSrc, pW, pb, h0, N, E);

    // pack all weights (hi/lo split)
    pack_w_kernel<<<dim3(32, 21, 1), 256, 0, stream>>>(Wl0, Wr0, Wl1, Wr1, outW1, Wph, Wpl);

    dim3 gemmGrid(MT, 2, 2);

    // ----- layer 0 (K=112 -> Kp=128, KT=4) -----
    pack_a_kernel<<<(Mp * 16 + 255) / 256, 256, 0, stream>>>(h0, Aph, Apl, N, 112, Mp, 4);
    for (int r = 0; r < 5; r++) {
        gemm_mfma<<<gemmGrid, 256, 0, stream>>>(
            Aph, Apl,
            Wph + oWl0 + r * S0, Wpl + oWl0 + r * S0, xl,
            Wph + oWr0 + r * S0, Wpl + oWr0 + r * S0, xr,
            N, 256, 4, nullptr, 0, 3, 1, 1);
        gat_kernel<<<(N + 3) / 4, 256, 0, stream>>>(xl, xr, att0 + (size_t)r * 256,
                                                    csrOff + (size_t)r * (N + 1),
                                                    csrSrc + (size_t)r * E, bufA,
                                                    (r == 0) ? b0 : nullptr, N, r == 4);
    }

    // ----- layer 1 (K=256, KT=8) -----
    pack_a_kernel<<<(Mp * 32 + 255) / 256, 256, 0, stream>>>(bufA, Aph, Apl, N, 256, Mp, 8);
    for (int r = 0; r < 5; r++) {
        gemm_mfma<<<gemmGrid, 256, 0, stream>>>(
            Aph, Apl,
            Wph + oWl1 + r * S1, Wpl + oWl1 + r * S1, xl,
            Wph + oWr1 + r * S1, Wpl + oWr1 + r * S1, xr,
            N, 256, 8, nullptr, 0, 3, 1, 1);
        gat_kernel<<<(N + 3) / 4, 256, 0, stream>>>(xl, xr, att1 + (size_t)r * 256,
                                                    csrOff + (size_t)r * (N + 1),
                                                    csrSrc + (size_t)r * E, bufB,
                                                    (r == 0) ? b1 : nullptr, N, r == 4);
    }

    // ----- MLP head: hmid = relu(bufB @ outW1 + outb1) -----
    pack_a_kernel<<<(Mp * 32 + 255) / 256, 256, 0, stream>>>(bufB, Aph, Apl, N, 256, Mp, 8);
    dim3 headGrid(MT, 1, 1);
    gemm_mfma<<<headGrid, 256, 0, stream>>>(
        Aph, Apl,
        Wph + oW1, Wpl + oW1, hmid,
        Wph + oW1, Wpl + oW1, hmid,
        N, 128, 8, outb1, 1, 3, 3, 0);
    head_kernel<<<(N + 3) / 4, 256, 0, stream>>>(hmid, outW2, outb2, out, N);
}

// Round 7
// 786.420 us; speedup vs baseline: 2.7631x; 1.2651x over previous
//
#include <hip/hip_runtime.h>
#include <math.h>

typedef __bf16 bf16x8 __attribute__((ext_vector_type(8)));
typedef float f32x4 __attribute__((ext_vector_type(4)));
typedef unsigned short u16x8 __attribute__((ext_vector_type(8)));

#define GLD16(src, dst)                                                        \
    __builtin_amdgcn_global_load_lds(                                          \
        (const __attribute__((address_space(1))) void*)(src),                  \
        (__attribute__((address_space(3))) void*)(dst), 16, 0, 0)

__device__ inline float bf2f(unsigned short u) {
    union { unsigned int i; float f; } c;
    c.i = ((unsigned int)u) << 16;
    return c.f;
}

// ---------------- CSR build ----------------

__global__ __launch_bounds__(256) void count_kernel(const int* __restrict__ ei,
                                                    int* __restrict__ cnt, int N, int E) {
    int idx = blockIdx.x * 256 + threadIdx.x;
    if (idx >= 5 * E) return;
    int r = idx / E;
    int e = idx - r * E;
    int dst = ei[(size_t)r * 2 * E + E + e];
    atomicAdd(&cnt[r * N + dst], 1);
}

__global__ __launch_bounds__(256) void scanA_kernel(const int* __restrict__ cnt,
                                                    int* __restrict__ off,
                                                    int* __restrict__ csums, int N, int NC) {
    int r = blockIdx.y, c = blockIdx.x, t = threadIdx.x;
    int idx0 = c * 1024 + t * 4;
    int v0 = (idx0 + 0 < N) ? cnt[r * N + idx0 + 0] : 0;
    int v1 = (idx0 + 1 < N) ? cnt[r * N + idx0 + 1] : 0;
    int v2 = (idx0 + 2 < N) ? cnt[r * N + idx0 + 2] : 0;
    int v3 = (idx0 + 3 < N) ? cnt[r * N + idx0 + 3] : 0;
    int ts = v0 + v1 + v2 + v3;
    __shared__ int sd[256];
    sd[t] = ts;
    __syncthreads();
    for (int s = 1; s < 256; s <<= 1) {
        int add = (t >= s) ? sd[t - s] : 0;
        __syncthreads();
        sd[t] += add;
        __syncthreads();
    }
    int excl = sd[t] - ts;
    size_t base = (size_t)r * (N + 1);
    if (idx0 + 0 < N) off[base + idx0 + 0] = excl;
    if (idx0 + 1 < N) off[base + idx0 + 1] = excl + v0;
    if (idx0 + 2 < N) off[base + idx0 + 2] = excl + v0 + v1;
    if (idx0 + 3 < N) off[base + idx0 + 3] = excl + v0 + v1 + v2;
    if (t == 255) csums[r * NC + c] = sd[255];
}

__global__ __launch_bounds__(64) void scanB_kernel(int* __restrict__ csums,
                                                   int* __restrict__ off, int N, int NC) {
    int r = threadIdx.x;
    if (r < 5) {
        int run = 0;
        for (int c = 0; c < NC; c++) {
            int t = csums[r * NC + c];
            csums[r * NC + c] = run;
            run += t;
        }
        off[(size_t)r * (N + 1) + N] = run;
    }
}

__global__ __launch_bounds__(256) void scanC_kernel(int* __restrict__ off,
                                                    const int* __restrict__ csums,
                                                    int N, int NC) {
    int r = blockIdx.y, c = blockIdx.x, t = threadIdx.x;
    int add = csums[r * NC + c];
    int idx0 = c * 1024 + t * 4;
    size_t base = (size_t)r * (N + 1);
#pragma unroll
    for (int j = 0; j < 4; j++)
        if (idx0 + j < N) off[base + idx0 + j] += add;
}

// src indices stored u16 (N < 65536): halves scatter write-allocate traffic
__global__ __launch_bounds__(256) void scatter_kernel(const int* __restrict__ ei,
                                                      const int* __restrict__ off,
                                                      int* __restrict__ cur,
                                                      unsigned short* __restrict__ srcs,
                                                      int N, int E) {
    int idx = blockIdx.x * 256 + threadIdx.x;
    if (idx >= 5 * E) return;
    int r = idx / E;
    int e = idx - r * E;
    int src = ei[(size_t)r * 2 * E + e];
    int dst = ei[(size_t)r * 2 * E + E + e];
    int pos = atomicAdd(&cur[r * N + dst], 1);
    srcs[(size_t)r * E + off[(size_t)r * (N + 1) + dst] + pos] = (unsigned short)src;
}

// ---------------- x -> bf16 copy (for pearl gather) ----------------

__global__ __launch_bounds__(256) void xcvt_kernel(const float* __restrict__ x,
                                                   unsigned short* __restrict__ xb, int total) {
    int idx = (blockIdx.x * 256 + threadIdx.x) * 4;
    if (idx >= total) return;
    float4 v = *(const float4*)(x + idx);
    __bf16 b0 = (__bf16)v.x, b1 = (__bf16)v.y, b2 = (__bf16)v.z, b3 = (__bf16)v.w;
    unsigned short* p = xb + idx;
    p[0] = *(unsigned short*)&b0;
    p[1] = *(unsigned short*)&b1;
    p[2] = *(unsigned short*)&b2;
    p[3] = *(unsigned short*)&b3;
}

// ---------------- PEARL PE + time PE + concat -> h0 [N,112] ----------------

__global__ __launch_bounds__(256) void pearl_h0_kernel(
    const float* __restrict__ x, const unsigned short* __restrict__ xb,
    const int* __restrict__ date,
    const int* __restrict__ off, const unsigned short* __restrict__ srcs,
    const float* __restrict__ pW, const float* __restrict__ pb,
    float* __restrict__ h0, int N, int E) {
    int lane = threadIdx.x & 63;
    int wid = blockIdx.x * 4 + (threadIdx.x >> 6);
    if (wid >= N) return;
    int n = __builtin_amdgcn_readfirstlane(wid);

    float acc = 0.f;
    int deg = 0;
    for (int r = 0; r < 5; r++) {
        int kb = off[(size_t)r * (N + 1) + n];
        int ke = off[(size_t)r * (N + 1) + n + 1];
        deg += ke - kb;
        const unsigned short* sp = srcs + (size_t)r * E;
        int k = kb;
        for (; k + 8 <= ke; k += 8) {
            int i0 = sp[k], i1 = sp[k + 1], i2 = sp[k + 2], i3 = sp[k + 3];
            int i4 = sp[k + 4], i5 = sp[k + 5], i6 = sp[k + 6], i7 = sp[k + 7];
            float a0 = bf2f(xb[(size_t)i0 * 64 + lane]);
            float a1 = bf2f(xb[(size_t)i1 * 64 + lane]);
            float a2 = bf2f(xb[(size_t)i2 * 64 + lane]);
            float a3 = bf2f(xb[(size_t)i3 * 64 + lane]);
            float a4 = bf2f(xb[(size_t)i4 * 64 + lane]);
            float a5 = bf2f(xb[(size_t)i5 * 64 + lane]);
            float a6 = bf2f(xb[(size_t)i6 * 64 + lane]);
            float a7 = bf2f(xb[(size_t)i7 * 64 + lane]);
            acc += ((a0 + a1) + (a2 + a3)) + ((a4 + a5) + (a6 + a7));
        }
        for (; k < ke; k++) acc += bf2f(xb[(size_t)sp[k] * 64 + lane]);
    }
    float an = acc / fmaxf((float)deg, 1.0f);

    float s = (lane < 32) ? pb[lane] : 0.f;
#pragma unroll 8
    for (int c = 0; c < 64; c++) {
        float av = __shfl(an, c, 64);
        if (lane < 32) s = fmaf(av, pW[c * 32 + lane], s);
    }

    h0[(size_t)n * 112 + lane] = x[(size_t)n * 64 + lane];
    if (lane < 32) h0[(size_t)n * 112 + 64 + lane] = tanhf(s);
    if (lane < 16) {
        float t = (float)date[n] / 10000.0f;
        int i = lane & 7;
        float dv = expf((float)(2 * i) * (-0.57564627324851148f));
        float arg = t * dv;
        h0[(size_t)n * 112 + 96 + lane] = (lane < 8) ? sinf(arg) : cosf(arg);
    }
}

// ---------------- pack A [M,K] fp32 -> hi/lo bf16, MFMA-fragment-major ----------------

__global__ __launch_bounds__(256) void pack_a_kernel(
    const float* __restrict__ A, __bf16* __restrict__ Ah, __bf16* __restrict__ Al,
    int M, int K, int Mp, int KT) {
    int KG = KT * 4;
    int idx = blockIdx.x * 256 + threadIdx.x;
    if (idx >= Mp * KG) return;
    int m = idx / KG, kgg = idx - m * KG;
    int kt = kgg >> 2, kg = kgg & 3;
    int k0 = kt * 32 + kg * 8;
    int mt = m >> 4, mr = m & 15;
    size_t out = (((size_t)mt * KT + kt) * 64 + kg * 16 + mr) * 8;
    bf16x8 hv, lv;
#pragma unroll
    for (int j = 0; j < 8; j++) {
        int k = k0 + j;
        float v = (m < M && k < K) ? A[(size_t)m * K + k] : 0.f;
        __bf16 h = (__bf16)v;
        hv[j] = h;
        lv[j] = (__bf16)(v - (float)h);
    }
    *(bf16x8*)(Ah + out) = hv;
    *(bf16x8*)(Al + out) = lv;
}

// ---------------- pack all weights (21 tensors, grid.y selects) ----------------

__global__ __launch_bounds__(256) void pack_w_kernel(
    const float* __restrict__ Wl0, const float* __restrict__ Wr0,
    const float* __restrict__ Wl1, const float* __restrict__ Wr1,
    const float* __restrict__ W1,
    __bf16* __restrict__ Wph, __bf16* __restrict__ Wpl) {
    const int S0 = 32768, S1 = 65536;
    int t = blockIdx.y;
    const float* W;
    int K, Nc, KT;
    size_t dst;
    if (t < 5)       { W = Wl0 + (size_t)t * 112 * 256;        K = 112; Nc = 256; KT = 4; dst = (size_t)t * S0; }
    else if (t < 10) { W = Wr0 + (size_t)(t - 5) * 112 * 256;  K = 112; Nc = 256; KT = 4; dst = 163840 + (size_t)(t - 5) * S0; }
    else if (t < 15) { W = Wl1 + (size_t)(t - 10) * 256 * 256; K = 256; Nc = 256; KT = 8; dst = 327680 + (size_t)(t - 10) * S1; }
    else if (t < 20) { W = Wr1 + (size_t)(t - 15) * 256 * 256; K = 256; Nc = 256; KT = 8; dst = 655360 + (size_t)(t - 15) * S1; }
    else             { W = W1;                                  K = 256; Nc = 128; KT = 8; dst = 983040; }
    int entries = (Nc / 16) * KT * 64;
    int idx = blockIdx.x * 256 + threadIdx.x;
    if (idx >= entries) return;
    int nt = idx / (KT * 64);
    int rem = idx - nt * (KT * 64);
    int kt = rem >> 6, lane = rem & 63;
    int kg = lane >> 4, nr = lane & 15;
    bf16x8 hv, lv;
#pragma unroll
    for (int j = 0; j < 8; j++) {
        int k = kt * 32 + kg * 8 + j;
        float v = (k < K) ? W[(size_t)k * Nc + nt * 16 + nr] : 0.f;
        __bf16 h = (__bf16)v;
        hv[j] = h;
        lv[j] = (__bf16)(v - (float)h);
    }
    *(bf16x8*)(Wph + dst + (size_t)idx * 8) = hv;
    *(bf16x8*)(Wpl + dst + (size_t)idx * 8) = lv;
}

// ---------------- split-bf16 MFMA GEMM, merged over (by, side, relation) ----------------
// Block decode from 1D grid, A-panel group (per_bx blocks) consecutive -> XCD L2 reuse.
// np: 3 = AhBh+AlBh+AhBl, 2 = AhBh+AlBh, 1 = AhBh.

__global__ __launch_bounds__(256) void gemm_mfma(
    const __bf16* __restrict__ Ah, const __bf16* __restrict__ Al,
    const __bf16* __restrict__ WLh, const __bf16* __restrict__ WLl,
    const __bf16* __restrict__ WRh, const __bf16* __restrict__ WRl,
    size_t strideB, void* __restrict__ Cl, void* __restrict__ Cr, size_t CstrideBytes,
    int M, int Nout, int KT, const float* __restrict__ bias, int do_relu,
    int npL, int npR, int out_bf16, int NYT, int per_bx) {
    int lin = blockIdx.x;
    int bx = lin / per_bx, rem = lin % per_bx;
    int by = rem % NYT; rem /= NYT;
    int side = rem & 1;
    int r = rem >> 1;

    const __bf16* Bh = (side ? WRh : WLh) + (size_t)r * strideB;
    const __bf16* Bl = (side ? WRl : WLl) + (size_t)r * strideB;
    char* C = (char*)(side ? Cr : Cl) + (size_t)r * CstrideBytes;
    int np = side ? npR : npL;

    __shared__ __bf16 sAh[8 * 512], sAl[8 * 512], sBh[8 * 512], sBl[8 * 512];

    int tid = threadIdx.x, lane = tid & 63, w = tid >> 6;
    int wr = w >> 1, wc = w & 1;

    f32x4 acc[4][4] = {};

    for (int kt = 0; kt < KT; ++kt) {
        int tl = w * 2;
        size_t a0 = ((size_t)(bx * 8 + tl) * KT + kt) * 512 + lane * 8;
        size_t a1 = ((size_t)(bx * 8 + tl + 1) * KT + kt) * 512 + lane * 8;
        size_t b0 = ((size_t)(by * 8 + tl) * KT + kt) * 512 + lane * 8;
        size_t b1 = ((size_t)(by * 8 + tl + 1) * KT + kt) * 512 + lane * 8;
        GLD16(Ah + a0, sAh + tl * 512);
        GLD16(Ah + a1, sAh + (tl + 1) * 512);
        GLD16(Bh + b0, sBh + tl * 512);
        GLD16(Bh + b1, sBh + (tl + 1) * 512);
        if (np >= 2) {
            GLD16(Al + a0, sAl + tl * 512);
            GLD16(Al + a1, sAl + (tl + 1) * 512);
        }
        if (np == 3) {
            GLD16(Bl + b0, sBl + tl * 512);
            GLD16(Bl + b1, sBl + (tl + 1) * 512);
        }
        __syncthreads();

        bf16x8 ah[4], al[4], bh[4], bl[4];
#pragma unroll
        for (int i = 0; i < 4; i++) {
            ah[i] = *(const bf16x8*)(sAh + (wr * 4 + i) * 512 + lane * 8);
            bh[i] = *(const bf16x8*)(sBh + (wc * 4 + i) * 512 + lane * 8);
        }
        if (np >= 2) {
#pragma unroll
            for (int i = 0; i < 4; i++)
                al[i] = *(const bf16x8*)(sAl + (wr * 4 + i) * 512 + lane * 8);
        }
        if (np == 3) {
#pragma unroll
            for (int i = 0; i < 4; i++)
                bl[i] = *(const bf16x8*)(sBl + (wc * 4 + i) * 512 + lane * 8);
        }
#pragma unroll
        for (int i = 0; i < 4; i++)
#pragma unroll
            for (int j = 0; j < 4; j++) {
                acc[i][j] = __builtin_amdgcn_mfma_f32_16x16x32_bf16(ah[i], bh[j], acc[i][j], 0, 0, 0);
                if (np >= 2)
                    acc[i][j] = __builtin_amdgcn_mfma_f32_16x16x32_bf16(al[i], bh[j], acc[i][j], 0, 0, 0);
                if (np == 3)
                    acc[i][j] = __builtin_amdgcn_mfma_f32_16x16x32_bf16(ah[i], bl[j], acc[i][j], 0, 0, 0);
            }
        __syncthreads();
    }

    int rb = bx * 128 + wr * 64, cb = by * 128 + wc * 64;
#pragma unroll
    for (int i = 0; i < 4; i++) {
#pragma unroll
        for (int j = 0; j < 4; j++) {
            int row0 = rb + i * 16 + (lane >> 4) * 4;
            int col = cb + j * 16 + (lane & 15);
            float bv = bias ? bias[col] : 0.f;
#pragma unroll
            for (int q = 0; q < 4; q++) {
                int row = row0 + q;
                if (row < M) {
                    float v = acc[i][j][q] + bv;
                    if (do_relu) v = fmaxf(v, 0.f);
                    if (out_bf16)
                        ((__bf16*)C)[(size_t)row * Nout + col] = (__bf16)v;
                    else
                        ((float*)C)[(size_t)row * Nout + col] = v;
                }
            }
        }
    }
}

// ---------------- fused GATv2 over ALL 5 relations: 4 edges/iter, bf16 gathers ----------------
// One wave per dst node; loops r=0..4 in-register; single conv write at the end.

__global__ __launch_bounds__(256) void gat5_kernel(
    const unsigned short* __restrict__ xl5, const unsigned short* __restrict__ xr5,
    const float* __restrict__ att,        // [5][256]
    const int* __restrict__ csrOff,       // [5][N+1]
    const unsigned short* __restrict__ csrSrc,  // [5][E]
    float* __restrict__ conv, const float* __restrict__ bvec,  // [5][256]
    int N, int E, int do_relu) {
    int lane = threadIdx.x & 63;
    int wid = blockIdx.x * 4 + (threadIdx.x >> 6);
    if (wid >= N) return;
    int n = __builtin_amdgcn_readfirstlane(wid);
    int e = lane >> 4;
    int sub = lane & 15;
    int cb = (sub >> 2) * 64 + (sub & 3) * 16;  // head*64 + q*16
    int wc = cb + e * 4;

    // bias init: sum of the 5 relations' bias rows (HeteroConv aggr='sum')
    float4 cv = {0.f, 0.f, 0.f, 0.f};
#pragma unroll
    for (int r = 0; r < 5; r++) {
        float4 b = *(const float4*)(bvec + r * 256 + wc);
        cv.x += b.x; cv.y += b.y; cv.z += b.z; cv.w += b.w;
    }

    for (int r = 0; r < 5; r++) {
        const unsigned short* xl = xl5 + (size_t)r * N * 256;
        float rv[16], av[16];
        {
            const unsigned short* xrp = xr5 + ((size_t)r * N + n) * 256 + cb;
            u16x8 q0 = *(const u16x8*)(xrp);
            u16x8 q1 = *(const u16x8*)(xrp + 8);
#pragma unroll
            for (int j = 0; j < 8; j++) { rv[j] = bf2f(q0[j]); rv[8 + j] = bf2f(q1[j]); }
#pragma unroll
            for (int j = 0; j < 16; j += 4) {
                float4 a = *(const float4*)(att + r * 256 + cb + j);
                av[j] = a.x; av[j + 1] = a.y; av[j + 2] = a.z; av[j + 3] = a.w;
            }
        }

        float m = -3.0e38f, d = 0.f;
        float A[16];
#pragma unroll
        for (int j = 0; j < 16; j++) A[j] = 0.f;

        const int* off = csrOff + (size_t)r * (N + 1);
        const unsigned short* sp = csrSrc + (size_t)r * E;
        int kb = off[n], ke = off[n + 1];
        if (kb < ke) {
            int kl = ke - 1;
            int ki = kb + e;
            int s = sp[(ki <= kl) ? ki : kl];
            float c[16];
            {
                const unsigned short* xp = xl + (size_t)s * 256 + cb;
                u16x8 q0 = *(const u16x8*)(xp);
                u16x8 q1 = *(const u16x8*)(xp + 8);
#pragma unroll
                for (int j = 0; j < 8; j++) { c[j] = bf2f(q0[j]); c[8 + j] = bf2f(q1[j]); }
            }
            for (int k = kb; k < ke; k += 4) {
                int kn = k + 4 + e;
                int sn = sp[(kn <= kl) ? kn : kl];
                const unsigned short* np_ = xl + (size_t)sn * 256 + cb;
                u16x8 n0 = *(const u16x8*)(np_);
                u16x8 n1 = *(const u16x8*)(np_ + 8);

                float p = 0.f;
#pragma unroll
                for (int j = 0; j < 16; j++) {
                    float t = c[j] + rv[j];
                    t = (t > 0.f) ? t : 0.2f * t;
                    p = fmaf(t, av[j], p);
                }
                p += __shfl_xor(p, 1, 64);
                p += __shfl_xor(p, 2, 64);
                bool valid = (k + e) < ke;
                if (!valid) p = -3.0e38f;

                if (__any(p > m)) {  // rare after warmup
                    float nm = fmaxf(m, p);
                    float sc = __expf(m - nm);
                    d *= sc;
#pragma unroll
                    for (int j = 0; j < 16; j++) A[j] *= sc;
                    m = nm;
                }
                float wg = valid ? __expf(p - m) : 0.f;
                d += wg;
#pragma unroll
                for (int j = 0; j < 16; j++) A[j] = fmaf(wg, c[j], A[j]);

#pragma unroll
                for (int j = 0; j < 8; j++) { c[j] = bf2f(n0[j]); c[8 + j] = bf2f(n1[j]); }
            }
        }

        // merge online-softmax state across the 4 e-groups
        float M = fmaxf(m, __shfl_xor(m, 16, 64));
        M = fmaxf(M, __shfl_xor(M, 32, 64));
        float sc = __expf(m - M);
        d *= sc;
        d += __shfl_xor(d, 16, 64);
        d += __shfl_xor(d, 32, 64);
#pragma unroll
        for (int j = 0; j < 16; j++) {
            A[j] *= sc;
            A[j] += __shfl_xor(A[j], 16, 64);
            A[j] += __shfl_xor(A[j], 32, 64);
        }

        float inv = 1.0f / (d + 1e-16f);
        cv.x = fmaf(A[e * 4 + 0], inv, cv.x);
        cv.y = fmaf(A[e * 4 + 1], inv, cv.y);
        cv.z = fmaf(A[e * 4 + 2], inv, cv.z);
        cv.w = fmaf(A[e * 4 + 3], inv, cv.w);
    }

    if (do_relu) {
        cv.x = fmaxf(cv.x, 0.f);
        cv.y = fmaxf(cv.y, 0.f);
        cv.z = fmaxf(cv.z, 0.f);
        cv.w = fmaxf(cv.w, 0.f);
    }
    *(float4*)(conv + (size_t)n * 256 + wc) = cv;
}

// ---------------- head ----------------

__global__ __launch_bounds__(256) void head_kernel(const float* __restrict__ hm,
                                                   const float* __restrict__ W2,
                                                   const float* __restrict__ b2,
                                                   float* __restrict__ out, int N) {
    int lane = threadIdx.x & 63;
    int wid = blockIdx.x * 4 + (threadIdx.x >> 6);
    if (wid >= N) return;
    int n = __builtin_amdgcn_readfirstlane(wid);
    float a0 = hm[(size_t)n * 128 + lane];
    float a1 = hm[(size_t)n * 128 + 64 + lane];
    float s0 = a0 * W2[lane * 3 + 0] + a1 * W2[(64 + lane) * 3 + 0];
    float s1 = a0 * W2[lane * 3 + 1] + a1 * W2[(64 + lane) * 3 + 1];
    float s2 = a0 * W2[lane * 3 + 2] + a1 * W2[(64 + lane) * 3 + 2];
#pragma unroll
    for (int sft = 1; sft < 64; sft <<= 1) {
        s0 += __shfl_xor(s0, sft, 64);
        s1 += __shfl_xor(s1, sft, 64);
        s2 += __shfl_xor(s2, sft, 64);
    }
    if (lane == 0) {
        out[(size_t)n * 3 + 0] = s0 + b2[0];
        out[(size_t)n * 3 + 1] = s1 + b2[1];
        out[(size_t)n * 3 + 2] = s2 + b2[2];
    }
}

// ---------------- launch ----------------

extern "C" void kernel_launch(void* const* d_in, const int* in_sizes, int n_in,
                              void* d_out, int out_size, void* d_ws, size_t ws_size,
                              hipStream_t stream) {
    const float* x    = (const float*)d_in[0];
    const int* date   = (const int*)d_in[1];
    const int* ei     = (const int*)d_in[2];
    const float* pW   = (const float*)d_in[3];
    const float* pb   = (const float*)d_in[4];
    const float* Wl0  = (const float*)d_in[5];
    const float* Wr0  = (const float*)d_in[6];
    const float* att0 = (const float*)d_in[7];
    const float* b0   = (const float*)d_in[8];
    const float* Wl1  = (const float*)d_in[9];
    const float* Wr1  = (const float*)d_in[10];
    const float* att1 = (const float*)d_in[11];
    const float* b1   = (const float*)d_in[12];
    // d_in[13..15] = aggW/aggb/agga — rel_agg is identity (h_rel broadcast), skipped
    const float* outW1 = (const float*)d_in[16];
    const float* outb1 = (const float*)d_in[17];
    const float* outW2 = (const float*)d_in[18];
    const float* outb2 = (const float*)d_in[19];
    float* out = (float*)d_out;

    int N = in_sizes[0] / 64;
    int E = in_sizes[2] / 10;
    int Mp = ((N + 127) / 128) * 128;
    int MT = Mp / 128;
    int NC = (N + 1023) / 1024;

    char* ws = (char*)d_ws;
    size_t o = 0;
    auto alloc = [&](size_t bytes) -> char* {
        char* p = ws + o;
        o += (bytes + 255) & ~(size_t)255;
        return p;
    };
    int* cur               = (int*)alloc((size_t)5 * N * 4);
    int* csrOff            = (int*)alloc((size_t)5 * (N + 1) * 4);
    unsigned short* csrSrc = (unsigned short*)alloc((size_t)5 * E * 2);
    int* csums             = (int*)alloc((size_t)5 * NC * 4);
    unsigned short* xb16   = (unsigned short*)alloc((size_t)N * 64 * 2);
    float* h0              = (float*)alloc((size_t)N * 112 * 4);
    float* conv            = (float*)alloc((size_t)N * 256 * 4);  // layer0 out, then layer1 out
    unsigned short* xl5    = (unsigned short*)alloc((size_t)5 * N * 256 * 2);
    unsigned short* xr5    = (unsigned short*)alloc((size_t)5 * N * 256 * 2);
    __bf16* Aph            = (__bf16*)alloc((size_t)Mp * 256 * 2);
    __bf16* Apl            = (__bf16*)alloc((size_t)Mp * 256 * 2);
    __bf16* Wph            = (__bf16*)alloc((size_t)1015808 * 2);
    __bf16* Wpl            = (__bf16*)alloc((size_t)1015808 * 2);
    float* hmid            = (float*)xl5;  // xl5 dead after layer-1 gat
    (void)ws_size;

    const size_t S0 = 32768, S1 = 65536;
    const size_t oWl0 = 0, oWr0 = 163840, oWl1 = 327680, oWr1 = 655360, oW1 = 983040;
    size_t xstride = (size_t)N * 256 * 2;  // bytes per relation slice

    int totE = 5 * E;

    // CSR by dst, per relation
    hipMemsetAsync(cur, 0, (size_t)5 * N * 4, stream);
    count_kernel<<<(totE + 255) / 256, 256, 0, stream>>>(ei, cur, N, E);
    scanA_kernel<<<dim3(NC, 5), 256, 0, stream>>>(cur, csrOff, csums, N, NC);
    scanB_kernel<<<1, 64, 0, stream>>>(csums, csrOff, N, NC);
    scanC_kernel<<<dim3(NC, 5), 256, 0, stream>>>(csrOff, csums, N, NC);
    hipMemsetAsync(cur, 0, (size_t)5 * N * 4, stream);
    scatter_kernel<<<(totE + 255) / 256, 256, 0, stream>>>(ei, csrOff, cur, csrSrc, N, E);

    // x -> bf16 copy + pearl PE + time PE + concat
    xcvt_kernel<<<(N * 64 / 4 + 255) / 256, 256, 0, stream>>>(x, xb16, N * 64);
    pearl_h0_kernel<<<(N + 3) / 4, 256, 0, stream>>>(x, xb16, date, csrOff, csrSrc, pW, pb, h0, N, E);

    // pack all weights (hi/lo split)
    pack_w_kernel<<<dim3(32, 21, 1), 256, 0, stream>>>(Wl0, Wr0, Wl1, Wr1, outW1, Wph, Wpl);

    // ----- layer 0 (K=112 -> Kp=128, KT=4): one GEMM launch (all 5 r, both sides) -----
    pack_a_kernel<<<(Mp * 16 + 255) / 256, 256, 0, stream>>>(h0, Aph, Apl, N, 112, Mp, 4);
    gemm_mfma<<<MT * 20, 256, 0, stream>>>(
        Aph, Apl, Wph + oWl0, Wpl + oWl0, Wph + oWr0, Wpl + oWr0, S0,
        xl5, xr5, xstride, N, 256, 4, nullptr, 0, 2, 1, 1, 2, 20);
    gat5_kernel<<<(N + 3) / 4, 256, 0, stream>>>(xl5, xr5, att0, csrOff, csrSrc,
                                                 conv, b0, N, E, 1);

    // ----- layer 1 (K=256, KT=8) -----
    pack_a_kernel<<<(Mp * 32 + 255) / 256, 256, 0, stream>>>(conv, Aph, Apl, N, 256, Mp, 8);
    gemm_mfma<<<MT * 20, 256, 0, stream>>>(
        Aph, Apl, Wph + oWl1, Wpl + oWl1, Wph + oWr1, Wpl + oWr1, S1,
        xl5, xr5, xstride, N, 256, 8, nullptr, 0, 2, 1, 1, 2, 20);
    gat5_kernel<<<(N + 3) / 4, 256, 0, stream>>>(xl5, xr5, att1, csrOff, csrSrc,
                                                 conv, b1, N, E, 1);

    // ----- MLP head: hmid = relu(conv @ outW1 + outb1) -----
    pack_a_kernel<<<(Mp * 32 + 255) / 256, 256, 0, stream>>>(conv, Aph, Apl, N, 256, Mp, 8);
    gemm_mfma<<<MT, 256, 0, stream>>>(
        Aph, Apl, Wph + oW1, Wpl + oW1, Wph + oW1, Wpl + oW1, 0,
        hmid, hmid, 0, N, 128, 8, outb1, 1, 3, 3, 0, 1, 1);
    head_kernel<<<(N + 3) / 4, 256, 0, stream>>>(hmid, outW2, outb2, out, N);
}